// Round 4
// baseline (507.048 us; speedup 1.0000x reference)
//
#include <hip/hip_runtime.h>

#define N_TOK 16384
#define HD 1024
#define ID 1024
#define NE 16
#define CAP 2560
#define NKA 32768   // N_TOK * K assignments

typedef _Float16 f16;
typedef _Float16 f16x4 __attribute__((ext_vector_type(4)));
typedef _Float16 f16x8 __attribute__((ext_vector_type(8)));
typedef float f32x4 __attribute__((ext_vector_type(4)));

#define MFMA16(a, b, c) __builtin_amdgcn_mfma_f32_16x16x32_f16(a, b, c, 0, 0, 0)

__device__ __forceinline__ void async16(f16* lds, const f16* g) {
  __builtin_amdgcn_global_load_lds(
      (const __attribute__((address_space(1))) unsigned int*)g,
      (__attribute__((address_space(3))) unsigned int*)lds, 16, 0, 0);
}

// ---------------- fp32 -> fp16 convert ----------------
__global__ void cvt_kernel(const float* __restrict__ src, f16* __restrict__ dst, int n4) {
  int i = blockIdx.x * blockDim.x + threadIdx.x;
  int stride = gridDim.x * blockDim.x;
  for (; i < n4; i += stride) {
    float4 v = ((const float4*)src)[i];
    f16x4 h = {(f16)v.x, (f16)v.y, (f16)v.z, (f16)v.w};
    ((f16x4*)dst)[i] = h;
  }
}

// ---------------- gating: logits, softmax, top-2 (no atomics) ----------------
__global__ void gate_kernel(const float* __restrict__ x, const float* __restrict__ gw,
                            int* __restrict__ tokE, float* __restrict__ tokW) {
  int t = blockIdx.x * 4 + (threadIdx.x >> 6);
  int lane = threadIdx.x & 63;
  const float4* xr = (const float4*)(x + (size_t)t * HD);
  const float4* gr = (const float4*)gw;
  float acc[NE];
#pragma unroll
  for (int e = 0; e < NE; e++) acc[e] = 0.f;
  for (int j = lane; j < HD / 4; j += 64) {
    float4 xv = xr[j];
#pragma unroll
    for (int e = 0; e < NE; e++) {
      float4 gv = gr[e * (HD / 4) + j];
      acc[e] += xv.x * gv.x + xv.y * gv.y + xv.z * gv.z + xv.w * gv.w;
    }
  }
#pragma unroll
  for (int e = 0; e < NE; e++) {
#pragma unroll
    for (int off = 32; off > 0; off >>= 1) acc[e] += __shfl_xor(acc[e], off);
  }
  if (lane == 0) {
    int i0 = 0;
#pragma unroll
    for (int e = 1; e < NE; e++) if (acc[e] > acc[i0]) i0 = e;
    int i1 = (i0 == 0) ? 1 : 0;
#pragma unroll
    for (int e = 0; e < NE; e++) if (e != i0 && acc[e] > acc[i1]) i1 = e;
    float mx = fmaxf(acc[i0], acc[i1]);
    float p0 = __expf(acc[i0] - mx), p1 = __expf(acc[i1] - mx);
    float inv = 1.f / (p0 + p1);
    tokE[t * 2] = i0;
    tokE[t * 2 + 1] = i1;
    tokW[t * 2] = p0 * inv;
    tokW[t * 2 + 1] = p1 * inv;
  }
}

// ---------------- bucket: ballot-compaction per expert (deterministic, atomic-free) ----------------
__global__ __launch_bounds__(1024) void bucket_kernel(
    const int* __restrict__ tokE, const float* __restrict__ tokW,
    int* __restrict__ cnt, int* __restrict__ bTok, float* __restrict__ bW,
    int* __restrict__ bFlat) {
  int e = blockIdx.x;
  int tid = threadIdx.x;  // 1024 = 16 waves
  int wid = tid >> 6, lane = tid & 63;
  __shared__ int wsum[16];
  __shared__ int wbase[16];
  __shared__ int chunkTotal;
  int total = 0;
  for (int c = 0; c < NKA; c += 1024) {
    int a = c + tid;
    bool pred = (tokE[a] == e);
    unsigned long long mask = __ballot(pred);
    int myrank = __popcll(mask & ((1ull << lane) - 1ull));
    if (lane == 0) wsum[wid] = __popcll(mask);
    __syncthreads();
    if (tid == 0) {
      int s = 0;
#pragma unroll
      for (int w = 0; w < 16; w++) { wbase[w] = s; s += wsum[w]; }
      chunkTotal = s;
    }
    __syncthreads();
    if (pred) {
      int pos = total + wbase[wid] + myrank;
      bTok[e * NKA + pos] = a >> 1;
      bW[e * NKA + pos] = tokW[a];
      bFlat[e * NKA + pos] = a;
    }
    total += chunkTotal;
    __syncthreads();
  }
  if (tid == 0) cnt[e] = total;
}

// ---------------- rank within expert + capacity selection ----------------
__global__ void rank_kernel(const int* __restrict__ cnt, int* __restrict__ mrows,
                            const int* __restrict__ bTok, const float* __restrict__ bW,
                            const int* __restrict__ bFlat, int* __restrict__ rowTok,
                            int* __restrict__ tokSlot) {
  int e = blockIdx.x, tid = threadIdx.x;
  int c = cnt[e];
  int m = c < CAP ? c : CAP;
  if (tid == 0) mrows[e] = m;
  if (c <= CAP) {
    for (int p = tid; p < c; p += blockDim.x) {
      int slot = e * CAP + p;
      rowTok[slot] = bTok[e * NKA + p];
      tokSlot[bFlat[e * NKA + p]] = slot;
    }
  } else {
    for (int p = tid; p < c; p += blockDim.x) {
      float wp = bW[e * NKA + p];
      int fp = bFlat[e * NKA + p];
      int rank = 0;
      for (int q = 0; q < c; q++) {
        float wq = bW[e * NKA + q];
        rank += (wq > wp) || (wq == wp && bFlat[e * NKA + q] < fp);
      }
      if (rank < CAP) {
        int slot = e * CAP + rank;
        rowTok[slot] = bTok[e * NKA + p];
        tokSlot[fp] = slot;
      } else {
        tokSlot[fp] = -1;
      }
    }
  }
}

// ---------------- GEMM1: gathered X @ {wg,wu}^T, fused silu*u -> GU fp16 ----------------
// BM=256 x BN=128(g)+128(u) x BK=64; 8 waves (2x4); 4-phase counted-vmcnt schedule
__global__ __launch_bounds__(512, 2) void gemm1_kernel(
    const f16* __restrict__ Xh, const f16* __restrict__ WGh, const f16* __restrict__ WUh,
    const int* __restrict__ rowTok, const int* __restrict__ mrows, f16* __restrict__ GU) {
  __shared__ __align__(16) f16 As[2][256 * 64];   // 64 KB
  __shared__ __align__(16) f16 Bg[2][128 * 64];   // 32 KB
  __shared__ __align__(16) f16 Bu[2][128 * 64];   // 32 KB

  int bid = ((int)blockIdx.x & 7) * 160 + ((int)blockIdx.x >> 3);  // XCD swizzle (1280 = 8*160)
  int e = bid / 80;
  int r = bid % 80;
  int rb = r / 8, cb = r % 8;
  int me = mrows[e];
  if (rb * 256 >= me) return;

  int tid = threadIdx.x;
  int wave = tid >> 6, lane = tid & 63;
  int wr = wave >> 2, wc = wave & 3;   // 2 x 4

  // A staging: 256x64 = 4 issues of (512 threads x 16B); gathered rows, pre-swizzled src
  const f16* aS[4];
  int aO[4];
#pragma unroll
  for (int j = 0; j < 4; j++) {
    int o = j * 512 + tid;
    int row = o >> 3, ch = o & 7;
    int rg = rb * 256 + row;
    int tok = (rg < me) ? rowTok[e * CAP + rg] : 0;
    aS[j] = Xh + (size_t)tok * HD + ((ch ^ (row & 7)) * 8);
    aO[j] = o * 8;
  }
  // B staging: 128x64 = 2 issues each for wg, wu
  const f16* gS[2];
  const f16* uS[2];
  int bO[2];
#pragma unroll
  for (int j = 0; j < 2; j++) {
    int o = j * 512 + tid;
    int row = o >> 3, ch = o & 7;
    size_t w = (size_t)e * ID * HD + (size_t)(cb * 128 + row) * HD + ((ch ^ (row & 7)) * 8);
    gS[j] = WGh + w;
    uS[j] = WUh + w;
    bO[j] = o * 8;
  }

  auto stageA = [&](int buf, int kt) {
    int kh = kt * 64;
#pragma unroll
    for (int j = 0; j < 4; j++) async16(&As[buf][aO[j]], aS[j] + kh);
  };
  auto stageB = [&](int buf, int kt) {
    int kh = kt * 64;
#pragma unroll
    for (int j = 0; j < 2; j++) {
      async16(&Bg[buf][bO[j]], gS[j] + kh);
      async16(&Bu[buf][bO[j]], uS[j] + kh);
    }
  };

  // prologue: B(0),A(0),B(1),A(1) -> 16 outstanding; wait for tile0 (8 left)
  stageB(0, 0); stageA(0, 0);
  stageB(1, 1); stageA(1, 1);
  asm volatile("s_waitcnt vmcnt(8)" ::: "memory");
  __builtin_amdgcn_sched_barrier(0);
  __builtin_amdgcn_s_barrier();
  __builtin_amdgcn_sched_barrier(0);

  f32x4 accg[8][2] = {};
  f32x4 accu[8][2] = {};
  f16x8 a[4][2], bg[2][2], bu[2][2];

  for (int t = 0; t < 16; t++) {
    int cur = t & 1;
    // ---- Q0: read a(m0-3) + bg; MFMA g-low
#pragma unroll
    for (int m = 0; m < 4; m++)
#pragma unroll
      for (int kk = 0; kk < 2; kk++) {
        int row = wr * 128 + m * 16 + (lane & 15);
        int c = (kk * 4 + (lane >> 4)) ^ (row & 7);
        a[m][kk] = *(const f16x8*)&As[cur][row * 64 + c * 8];
      }
#pragma unroll
    for (int n = 0; n < 2; n++)
#pragma unroll
      for (int kk = 0; kk < 2; kk++) {
        int row = wc * 32 + n * 16 + (lane & 15);
        int c = (kk * 4 + (lane >> 4)) ^ (row & 7);
        bg[n][kk] = *(const f16x8*)&Bg[cur][row * 64 + c * 8];
      }
    asm volatile("s_waitcnt lgkmcnt(0)" ::: "memory");
    __builtin_amdgcn_sched_barrier(0);
    __builtin_amdgcn_s_setprio(1);
#pragma unroll
    for (int kk = 0; kk < 2; kk++)
#pragma unroll
      for (int m = 0; m < 4; m++)
#pragma unroll
        for (int n = 0; n < 2; n++)
          accg[m][n] = MFMA16(a[m][kk], bg[n][kk], accg[m][n]);
    __builtin_amdgcn_s_setprio(0);
    __builtin_amdgcn_sched_barrier(0);
    __builtin_amdgcn_s_barrier();
    __builtin_amdgcn_sched_barrier(0);
    // ---- Q1: read bu; MFMA u-low
#pragma unroll
    for (int n = 0; n < 2; n++)
#pragma unroll
      for (int kk = 0; kk < 2; kk++) {
        int row = wc * 32 + n * 16 + (lane & 15);
        int c = (kk * 4 + (lane >> 4)) ^ (row & 7);
        bu[n][kk] = *(const f16x8*)&Bu[cur][row * 64 + c * 8];
      }
    asm volatile("s_waitcnt lgkmcnt(0)" ::: "memory");
    __builtin_amdgcn_sched_barrier(0);
    __builtin_amdgcn_s_setprio(1);
#pragma unroll
    for (int kk = 0; kk < 2; kk++)
#pragma unroll
      for (int m = 0; m < 4; m++)
#pragma unroll
        for (int n = 0; n < 2; n++)
          accu[m][n] = MFMA16(a[m][kk], bu[n][kk], accu[m][n]);
    __builtin_amdgcn_s_setprio(0);
    __builtin_amdgcn_sched_barrier(0);
    __builtin_amdgcn_s_barrier();
    __builtin_amdgcn_sched_barrier(0);
    // ---- Q2: stage B(t+2) (B region of buf cur free); read a(m4-7); MFMA g-high
    if (t < 14) stageB(cur, t + 2);
#pragma unroll
    for (int m = 0; m < 4; m++)
#pragma unroll
      for (int kk = 0; kk < 2; kk++) {
        int row = wr * 128 + (m + 4) * 16 + (lane & 15);
        int c = (kk * 4 + (lane >> 4)) ^ (row & 7);
        a[m][kk] = *(const f16x8*)&As[cur][row * 64 + c * 8];
      }
    asm volatile("s_waitcnt lgkmcnt(0)" ::: "memory");
    __builtin_amdgcn_sched_barrier(0);
    __builtin_amdgcn_s_setprio(1);
#pragma unroll
    for (int kk = 0; kk < 2; kk++)
#pragma unroll
      for (int m = 0; m < 4; m++)
#pragma unroll
        for (int n = 0; n < 2; n++)
          accg[m + 4][n] = MFMA16(a[m][kk], bg[n][kk], accg[m + 4][n]);
    __builtin_amdgcn_s_setprio(0);
    __builtin_amdgcn_sched_barrier(0);
    __builtin_amdgcn_s_barrier();
    __builtin_amdgcn_sched_barrier(0);
    // ---- Q3: stage A(t+2) (A region free); MFMA u-high; counted vmcnt; barrier
    if (t < 14) stageA(cur, t + 2);
    __builtin_amdgcn_sched_barrier(0);
    __builtin_amdgcn_s_setprio(1);
#pragma unroll
    for (int kk = 0; kk < 2; kk++)
#pragma unroll
      for (int m = 0; m < 4; m++)
#pragma unroll
        for (int n = 0; n < 2; n++)
          accu[m + 4][n] = MFMA16(a[m][kk], bu[n][kk], accu[m + 4][n]);
    __builtin_amdgcn_s_setprio(0);
    __builtin_amdgcn_sched_barrier(0);
    if (t < 14) asm volatile("s_waitcnt vmcnt(8)" ::: "memory");
    else        asm volatile("s_waitcnt vmcnt(0)" ::: "memory");
    __builtin_amdgcn_sched_barrier(0);
    __builtin_amdgcn_s_barrier();
    __builtin_amdgcn_sched_barrier(0);
  }

  int rbase = e * CAP + rb * 256 + wr * 128;
  int cbase = cb * 128 + wc * 32;
#pragma unroll
  for (int m = 0; m < 8; m++)
#pragma unroll
    for (int n = 0; n < 2; n++)
#pragma unroll
      for (int rr = 0; rr < 4; rr++) {
        int row = rbase + m * 16 + (lane >> 4) * 4 + rr;
        int col = cbase + n * 16 + (lane & 15);
        float g = accg[m][n][rr];
        float u = accu[m][n][rr];
        float s = g / (1.f + __expf(-g));
        GU[(size_t)row * ID + col] = (f16)(s * u);
      }
}

// ---------------- GEMM2: GU @ wd^T -> OE fp16 ----------------
// BM=256 x BN=256 x BK=64; 8 waves (2x4); 4-phase counted-vmcnt schedule
__global__ __launch_bounds__(512, 2) void gemm2_kernel(
    const f16* __restrict__ GU, const f16* __restrict__ WDh,
    const int* __restrict__ mrows, f16* __restrict__ OE) {
  __shared__ __align__(16) f16 As[2][256 * 64];   // 64 KB
  __shared__ __align__(16) f16 Bs[2][256 * 64];   // 64 KB

  int bid = ((int)blockIdx.x & 7) * 80 + ((int)blockIdx.x >> 3);  // XCD swizzle (640 = 8*80)
  int e = bid / 40;
  int r = bid % 40;
  int rb = r / 4, cb = r % 4;
  if (rb * 256 >= mrows[e]) return;

  int tid = threadIdx.x;
  int wave = tid >> 6, lane = tid & 63;
  int wr = wave >> 2, wc = wave & 3;   // 2 x 4

  const f16* aS[4];
  const f16* bS[4];
  int sO[4];
#pragma unroll
  for (int j = 0; j < 4; j++) {
    int o = j * 512 + tid;
    int row = o >> 3, ch = o & 7;
    int sw = (ch ^ (row & 7)) * 8;
    aS[j] = GU + (size_t)(e * CAP + rb * 256 + row) * ID + sw;
    bS[j] = WDh + (size_t)e * HD * ID + (size_t)(cb * 256 + row) * ID + sw;
    sO[j] = o * 8;
  }

  auto stageA = [&](int buf, int kt) {
    int kh = kt * 64;
#pragma unroll
    for (int j = 0; j < 4; j++) async16(&As[buf][sO[j]], aS[j] + kh);
  };
  auto stageB = [&](int buf, int kt) {
    int kh = kt * 64;
#pragma unroll
    for (int j = 0; j < 4; j++) async16(&Bs[buf][sO[j]], bS[j] + kh);
  };

  stageB(0, 0); stageA(0, 0);
  stageB(1, 1); stageA(1, 1);
  asm volatile("s_waitcnt vmcnt(8)" ::: "memory");
  __builtin_amdgcn_sched_barrier(0);
  __builtin_amdgcn_s_barrier();
  __builtin_amdgcn_sched_barrier(0);

  f32x4 acc[8][4] = {};
  f16x8 a[4][2], b[4][2];

  for (int t = 0; t < 16; t++) {
    int cur = t & 1;
    // ---- Q0: read a(m0-3) + b(n0-1); MFMA m-low x n-low
#pragma unroll
    for (int m = 0; m < 4; m++)
#pragma unroll
      for (int kk = 0; kk < 2; kk++) {
        int row = wr * 128 + m * 16 + (lane & 15);
        int c = (kk * 4 + (lane >> 4)) ^ (row & 7);
        a[m][kk] = *(const f16x8*)&As[cur][row * 64 + c * 8];
      }
#pragma unroll
    for (int n = 0; n < 2; n++)
#pragma unroll
      for (int kk = 0; kk < 2; kk++) {
        int row = wc * 64 + n * 16 + (lane & 15);
        int c = (kk * 4 + (lane >> 4)) ^ (row & 7);
        b[n][kk] = *(const f16x8*)&Bs[cur][row * 64 + c * 8];
      }
    asm volatile("s_waitcnt lgkmcnt(0)" ::: "memory");
    __builtin_amdgcn_sched_barrier(0);
    __builtin_amdgcn_s_setprio(1);
#pragma unroll
    for (int kk = 0; kk < 2; kk++)
#pragma unroll
      for (int m = 0; m < 4; m++)
#pragma unroll
        for (int n = 0; n < 2; n++)
          acc[m][n] = MFMA16(a[m][kk], b[n][kk], acc[m][n]);
    __builtin_amdgcn_s_setprio(0);
    __builtin_amdgcn_sched_barrier(0);
    __builtin_amdgcn_s_barrier();
    __builtin_amdgcn_sched_barrier(0);
    // ---- Q1: read b(n2-3); MFMA m-low x n-high
#pragma unroll
    for (int n = 0; n < 2; n++)
#pragma unroll
      for (int kk = 0; kk < 2; kk++) {
        int row = wc * 64 + (n + 2) * 16 + (lane & 15);
        int c = (kk * 4 + (lane >> 4)) ^ (row & 7);
        b[n + 2][kk] = *(const f16x8*)&Bs[cur][row * 64 + c * 8];
      }
    asm volatile("s_waitcnt lgkmcnt(0)" ::: "memory");
    __builtin_amdgcn_sched_barrier(0);
    __builtin_amdgcn_s_setprio(1);
#pragma unroll
    for (int kk = 0; kk < 2; kk++)
#pragma unroll
      for (int m = 0; m < 4; m++)
#pragma unroll
        for (int n = 0; n < 2; n++)
          acc[m][n + 2] = MFMA16(a[m][kk], b[n + 2][kk], acc[m][n + 2]);
    __builtin_amdgcn_s_setprio(0);
    __builtin_amdgcn_sched_barrier(0);
    __builtin_amdgcn_s_barrier();
    __builtin_amdgcn_sched_barrier(0);
    // ---- Q2: stage B(t+2); read a(m4-7); MFMA m-high x n-low
    if (t < 14) stageB(cur, t + 2);
#pragma unroll
    for (int m = 0; m < 4; m++)
#pragma unroll
      for (int kk = 0; kk < 2; kk++) {
        int row = wr * 128 + (m + 4) * 16 + (lane & 15);
        int c = (kk * 4 + (lane >> 4)) ^ (row & 7);
        a[m][kk] = *(const f16x8*)&As[cur][row * 64 + c * 8];
      }
    asm volatile("s_waitcnt lgkmcnt(0)" ::: "memory");
    __builtin_amdgcn_sched_barrier(0);
    __builtin_amdgcn_s_setprio(1);
#pragma unroll
    for (int kk = 0; kk < 2; kk++)
#pragma unroll
      for (int m = 0; m < 4; m++)
#pragma unroll
        for (int n = 0; n < 2; n++)
          acc[m + 4][n] = MFMA16(a[m][kk], b[n][kk], acc[m + 4][n]);
    __builtin_amdgcn_s_setprio(0);
    __builtin_amdgcn_sched_barrier(0);
    __builtin_amdgcn_s_barrier();
    __builtin_amdgcn_sched_barrier(0);
    // ---- Q3: stage A(t+2); MFMA m-high x n-high; counted vmcnt; barrier
    if (t < 14) stageA(cur, t + 2);
    __builtin_amdgcn_sched_barrier(0);
    __builtin_amdgcn_s_setprio(1);
#pragma unroll
    for (int kk = 0; kk < 2; kk++)
#pragma unroll
      for (int m = 0; m < 4; m++)
#pragma unroll
        for (int n = 0; n < 2; n++)
          acc[m + 4][n + 2] = MFMA16(a[m][kk], b[n + 2][kk], acc[m + 4][n + 2]);
    __builtin_amdgcn_s_setprio(0);
    __builtin_amdgcn_sched_barrier(0);
    if (t < 14) asm volatile("s_waitcnt vmcnt(8)" ::: "memory");
    else        asm volatile("s_waitcnt vmcnt(0)" ::: "memory");
    __builtin_amdgcn_sched_barrier(0);
    __builtin_amdgcn_s_barrier();
    __builtin_amdgcn_sched_barrier(0);
  }

  int rbase = e * CAP + rb * 256 + wr * 128;
  int cbase = cb * 256 + wc * 64;
#pragma unroll
  for (int m = 0; m < 8; m++)
#pragma unroll
    for (int n = 0; n < 4; n++)
#pragma unroll
      for (int rr = 0; rr < 4; rr++) {
        int row = rbase + m * 16 + (lane >> 4) * 4 + rr;
        int col = cbase + n * 16 + (lane & 15);
        OE[(size_t)row * HD + col] = (f16)acc[m][n][rr];
      }
}

// ---------------- combine: out[t] = sum_k w_k * OE[slot_k] ----------------
__global__ void combine_kernel(const f16* __restrict__ OE, const int* __restrict__ tokSlot,
                               const float* __restrict__ tokW, float* __restrict__ out) {
  int t = blockIdx.x, tid = threadIdx.x;
  int s0 = tokSlot[t * 2], s1 = tokSlot[t * 2 + 1];
  float w0 = tokW[t * 2], w1 = tokW[t * 2 + 1];
  int c = tid * 4;
  float4 o = {0.f, 0.f, 0.f, 0.f};
  if (s0 >= 0) {
    f16x4 v = *(const f16x4*)&OE[(size_t)s0 * HD + c];
    o.x += w0 * (float)v[0]; o.y += w0 * (float)v[1];
    o.z += w0 * (float)v[2]; o.w += w0 * (float)v[3];
  }
  if (s1 >= 0) {
    f16x4 v = *(const f16x4*)&OE[(size_t)s1 * HD + c];
    o.x += w1 * (float)v[0]; o.y += w1 * (float)v[1];
    o.z += w1 * (float)v[2]; o.w += w1 * (float)v[3];
  }
  *(float4*)&out[(size_t)t * HD + c] = o;
  if (t == 0 && tid == 0) out[(size_t)N_TOK * HD] = 0.f;  // aux_loss
}

extern "C" void kernel_launch(void* const* d_in, const int* in_sizes, int n_in,
                              void* d_out, int out_size, void* d_ws, size_t ws_size,
                              hipStream_t stream) {
  (void)in_sizes; (void)n_in; (void)out_size; (void)ws_size;
  const float* x  = (const float*)d_in[0];
  const float* gw = (const float*)d_in[1];
  const float* wg = (const float*)d_in[2];
  const float* wu = (const float*)d_in[3];
  const float* wd = (const float*)d_in[4];
  float* out = (float*)d_out;

  char* ws = (char*)d_ws;
  f16* Xh  = (f16*)ws;                          // 32 MB
  f16* WGh = (f16*)(ws + 33554432ll);           // 32 MB
  f16* WUh = (f16*)(ws + 67108864ll);           // 32 MB
  f16* WDh = (f16*)(ws + 100663296ll);          // 32 MB
  f16* GU  = (f16*)(ws + 134217728ll);          // 80 MB
  f16* OE  = (f16*)ws;                          // aliases Xh/WGh (dead by GEMM2)
  char* rt = ws + 218103808ll;
  int*   cnt     = (int*)rt;                    // 64 B
  int*   mrows   = (int*)(rt + 64);             // 64 B
  int*   rowTok  = (int*)(rt + 128);            // 160 KB
  int*   tokSlot = (int*)(rt + 128 + 163840);   // 128 KB
  float* tokW    = (float*)(rt + 128 + 163840 + 131072);
  char*  rb      = rt + 128 + 163840 + 131072 + 131072;
  int*   bTok  = (int*)rb;                      // 2 MB
  float* bW    = (float*)(rb + 2097152);        // 2 MB
  int*   bFlat = (int*)(rb + 4194304);          // 2 MB
  int*   tokE  = (int*)(rb + 6291456);          // 128 KB

  cvt_kernel<<<4096, 256, 0, stream>>>(x,  Xh,  N_TOK * HD / 4);
  cvt_kernel<<<4096, 256, 0, stream>>>(wg, WGh, NE * ID * HD / 4);
  cvt_kernel<<<4096, 256, 0, stream>>>(wu, WUh, NE * ID * HD / 4);
  cvt_kernel<<<4096, 256, 0, stream>>>(wd, WDh, NE * HD * ID / 4);
  gate_kernel<<<N_TOK / 4, 256, 0, stream>>>(x, gw, tokE, tokW);
  bucket_kernel<<<NE, 1024, 0, stream>>>(tokE, tokW, cnt, bTok, bW, bFlat);
  rank_kernel<<<NE, 256, 0, stream>>>(cnt, mrows, bTok, bW, bFlat, rowTok, tokSlot);
  gemm1_kernel<<<NE * 10 * 8, 512, 0, stream>>>(Xh, WGh, WUh, rowTok, mrows, GU);
  gemm2_kernel<<<NE * 10 * 4, 512, 0, stream>>>(GU, WDh, mrows, OE);
  combine_kernel<<<N_TOK, 256, 0, stream>>>(OE, tokSlot, tokW, out);
}

// Round 5
// 458.957 us; speedup vs baseline: 1.1048x; 1.1048x over previous
//
#include <hip/hip_runtime.h>

#define N_TOK 16384
#define HD 1024
#define ID 1024
#define NE 16
#define CAP 2560
#define NKA 32768   // N_TOK * K assignments

typedef _Float16 f16;
typedef _Float16 f16x4 __attribute__((ext_vector_type(4)));
typedef _Float16 f16x8 __attribute__((ext_vector_type(8)));
typedef float f32x4 __attribute__((ext_vector_type(4)));

#define MFMA16(a, b, c) __builtin_amdgcn_mfma_f32_16x16x32_f16(a, b, c, 0, 0, 0)
#define SB __builtin_amdgcn_sched_barrier(0)
#define BAR __builtin_amdgcn_s_barrier()
#define LGKM0 do { asm volatile("s_waitcnt lgkmcnt(0)" ::: "memory"); SB; } while (0)

__device__ __forceinline__ void async16(f16* lds, const f16* g) {
  __builtin_amdgcn_global_load_lds(
      (const __attribute__((address_space(1))) unsigned int*)g,
      (__attribute__((address_space(3))) unsigned int*)lds, 16, 0, 0);
}

// ---------------- fp32 -> fp16 convert: 3 weight tensors in one launch ----------------
__global__ void cvt3_kernel(const float* __restrict__ s0, const float* __restrict__ s1,
                            const float* __restrict__ s2, f16* __restrict__ d0,
                            f16* __restrict__ d1, f16* __restrict__ d2, int n4) {
  int start = blockIdx.x * blockDim.x + threadIdx.x;
  int stride = gridDim.x * blockDim.x;
  for (int i = start; i < n4; i += stride) {
    float4 v = ((const float4*)s0)[i];
    f16x4 h = {(f16)v.x, (f16)v.y, (f16)v.z, (f16)v.w};
    ((f16x4*)d0)[i] = h;
  }
  for (int i = start; i < n4; i += stride) {
    float4 v = ((const float4*)s1)[i];
    f16x4 h = {(f16)v.x, (f16)v.y, (f16)v.z, (f16)v.w};
    ((f16x4*)d1)[i] = h;
  }
  for (int i = start; i < n4; i += stride) {
    float4 v = ((const float4*)s2)[i];
    f16x4 h = {(f16)v.x, (f16)v.y, (f16)v.z, (f16)v.w};
    ((f16x4*)d2)[i] = h;
  }
}

// ---------------- gating: logits, softmax, top-2; also emits Xh (fp16 x) ----------------
__global__ void gate_kernel(const float* __restrict__ x, const float* __restrict__ gw,
                            int* __restrict__ tokE, float* __restrict__ tokW,
                            f16* __restrict__ Xh) {
  int t = blockIdx.x * 4 + (threadIdx.x >> 6);
  int lane = threadIdx.x & 63;
  const float4* xr = (const float4*)(x + (size_t)t * HD);
  const float4* gr = (const float4*)gw;
  f16x4* xw = (f16x4*)(Xh + (size_t)t * HD);
  float acc[NE];
#pragma unroll
  for (int e = 0; e < NE; e++) acc[e] = 0.f;
  for (int j = lane; j < HD / 4; j += 64) {
    float4 xv = xr[j];
    f16x4 h = {(f16)xv.x, (f16)xv.y, (f16)xv.z, (f16)xv.w};
    xw[j] = h;
#pragma unroll
    for (int e = 0; e < NE; e++) {
      float4 gv = gr[e * (HD / 4) + j];
      acc[e] += xv.x * gv.x + xv.y * gv.y + xv.z * gv.z + xv.w * gv.w;
    }
  }
#pragma unroll
  for (int e = 0; e < NE; e++) {
#pragma unroll
    for (int off = 32; off > 0; off >>= 1) acc[e] += __shfl_xor(acc[e], off);
  }
  if (lane == 0) {
    int i0 = 0;
#pragma unroll
    for (int e = 1; e < NE; e++) if (acc[e] > acc[i0]) i0 = e;
    int i1 = (i0 == 0) ? 1 : 0;
#pragma unroll
    for (int e = 0; e < NE; e++) if (e != i0 && acc[e] > acc[i1]) i1 = e;
    float mx = fmaxf(acc[i0], acc[i1]);
    float p0 = __expf(acc[i0] - mx), p1 = __expf(acc[i1] - mx);
    float inv = 1.f / (p0 + p1);
    tokE[t * 2] = i0;
    tokE[t * 2 + 1] = i1;
    tokW[t * 2] = p0 * inv;
    tokW[t * 2 + 1] = p1 * inv;
  }
}

// ---------------- bucket: ballot-compaction per expert (deterministic, atomic-free) ----------------
__global__ __launch_bounds__(1024) void bucket_kernel(
    const int* __restrict__ tokE, const float* __restrict__ tokW,
    int* __restrict__ cnt, int* __restrict__ bTok, float* __restrict__ bW,
    int* __restrict__ bFlat) {
  int e = blockIdx.x;
  int tid = threadIdx.x;  // 1024 = 16 waves
  int wid = tid >> 6, lane = tid & 63;
  __shared__ int wsum[16];
  __shared__ int wbase[16];
  __shared__ int chunkTotal;
  int total = 0;
  for (int c = 0; c < NKA; c += 1024) {
    int a = c + tid;
    bool pred = (tokE[a] == e);
    unsigned long long mask = __ballot(pred);
    int myrank = __popcll(mask & ((1ull << lane) - 1ull));
    if (lane == 0) wsum[wid] = __popcll(mask);
    __syncthreads();
    if (tid == 0) {
      int s = 0;
#pragma unroll
      for (int w = 0; w < 16; w++) { wbase[w] = s; s += wsum[w]; }
      chunkTotal = s;
    }
    __syncthreads();
    if (pred) {
      int pos = total + wbase[wid] + myrank;
      bTok[e * NKA + pos] = a >> 1;
      bW[e * NKA + pos] = tokW[a];
      bFlat[e * NKA + pos] = a;
    }
    total += chunkTotal;
    __syncthreads();
  }
  if (tid == 0) cnt[e] = total;
}

// ---------------- rank within expert + capacity selection ----------------
__global__ void rank_kernel(const int* __restrict__ cnt, int* __restrict__ mrows,
                            const int* __restrict__ bTok, const float* __restrict__ bW,
                            const int* __restrict__ bFlat, int* __restrict__ rowTok,
                            int* __restrict__ tokSlot) {
  int e = blockIdx.x, tid = threadIdx.x;
  int c = cnt[e];
  int m = c < CAP ? c : CAP;
  if (tid == 0) mrows[e] = m;
  if (c <= CAP) {
    for (int p = tid; p < c; p += blockDim.x) {
      int slot = e * CAP + p;
      rowTok[slot] = bTok[e * NKA + p];
      tokSlot[bFlat[e * NKA + p]] = slot;
    }
  } else {
    for (int p = tid; p < c; p += blockDim.x) {
      float wp = bW[e * NKA + p];
      int fp = bFlat[e * NKA + p];
      int rank = 0;
      for (int q = 0; q < c; q++) {
        float wq = bW[e * NKA + q];
        rank += (wq > wp) || (wq == wp && bFlat[e * NKA + q] < fp);
      }
      if (rank < CAP) {
        int slot = e * CAP + rank;
        rowTok[slot] = bTok[e * NKA + p];
        tokSlot[fp] = slot;
      } else {
        tokSlot[fp] = -1;
      }
    }
  }
}

// ---------------- GEMM1: gathered X @ {wg,wu}^T, fused silu*u -> GU fp16 ----------------
// BM=256 x (128 g + 128 u) x BK=64; 8 waves (2m x 4n), per-wave 128x(32g+32u).
// 4 phases/K-tile, each: {quadrant ds_reads; 1 half-tile stage} -> BAR -> lgkm0 -> 16 MFMA -> BAR.
// Stage ledger (freed-at verified): Ah1(t+1)@P0, Bg(t+2)@P1, Bu(t+2)@P2, Ah0(t+2)@P3; vmcnt(6)@P3.
__global__ __launch_bounds__(512, 2) void gemm1_kernel(
    const f16* __restrict__ Xh, const f16* __restrict__ WGh, const f16* __restrict__ WUh,
    const int* __restrict__ rowTok, const int* __restrict__ mrows, f16* __restrict__ GU) {
  __shared__ __align__(16) f16 As[2][256 * 64];   // 64 KB
  __shared__ __align__(16) f16 Bg[2][128 * 64];   // 32 KB
  __shared__ __align__(16) f16 Bu[2][128 * 64];   // 32 KB

  int bid = ((int)blockIdx.x & 7) * 160 + ((int)blockIdx.x >> 3);  // XCD swizzle (1280 = 8*160)
  int e = bid / 80;
  int r = bid % 80;
  int rb = r / 8, cb = r % 8;
  int me = mrows[e];
  if (rb * 256 >= me) return;

  int tid = threadIdx.x;
  int wave = tid >> 6, lane = tid & 63;
  int wr = wave >> 2, wc = wave & 3;   // 2 x 4

  // A: 256x64, 8 issues of (512 thr x 16B); j=0,1 -> rows 0..127 (Ah0), j=2,3 -> 128..255 (Ah1)
  const f16* aS[4];
  int aO[4];
#pragma unroll
  for (int j = 0; j < 4; j++) {
    int o = j * 512 + tid;
    int row = o >> 3, ch = o & 7;
    int rg = rb * 256 + row;
    int tok = (rg < me) ? rowTok[e * CAP + rg] : 0;
    aS[j] = Xh + (size_t)tok * HD + ((ch ^ (row & 7)) * 8);
    aO[j] = o * 8;
  }
  // B: 128x64 each, 2 issues
  const f16* gS[2];
  const f16* uS[2];
  int bO[2];
#pragma unroll
  for (int j = 0; j < 2; j++) {
    int o = j * 512 + tid;
    int row = o >> 3, ch = o & 7;
    size_t w = (size_t)e * ID * HD + (size_t)(cb * 128 + row) * HD + ((ch ^ (row & 7)) * 8);
    gS[j] = WGh + w;
    uS[j] = WUh + w;
    bO[j] = o * 8;
  }

  auto stAh0 = [&](int tile) { int bf = tile & 1, kh = tile * 64;
    async16(&As[bf][aO[0]], aS[0] + kh); async16(&As[bf][aO[1]], aS[1] + kh); };
  auto stAh1 = [&](int tile) { int bf = tile & 1, kh = tile * 64;
    async16(&As[bf][aO[2]], aS[2] + kh); async16(&As[bf][aO[3]], aS[3] + kh); };
  auto stBg = [&](int tile) { int bf = tile & 1, kh = tile * 64;
    async16(&Bg[bf][bO[0]], gS[0] + kh); async16(&Bg[bf][bO[1]], gS[1] + kh); };
  auto stBu = [&](int tile) { int bf = tile & 1, kh = tile * 64;
    async16(&Bu[bf][bO[0]], uS[0] + kh); async16(&Bu[bf][bO[1]], uS[1] + kh); };

  // prologue: tiles 0 and 1 fully staged (16 loads/wave); wait tile0 (8 left)
  stBg(0); stBu(0); stAh0(0); stAh1(0);
  stBg(1); stBu(1); stAh0(1); stAh1(1);
  asm volatile("s_waitcnt vmcnt(8)" ::: "memory");
  SB; BAR; SB;

  f32x4 accg[8][2] = {};
  f32x4 accu[8][2] = {};
  f16x8 a[4][2], bgf[2][2], buf_[2][2];

  for (int t = 0; t < 16; t++) {
    int cur = t & 1;
    // ======== P0: reads a0-3 + bg; stage Ah1(t+1); MFMA g-low ========
#pragma unroll
    for (int m = 0; m < 4; m++)
#pragma unroll
      for (int kk = 0; kk < 2; kk++) {
        int row = wr * 128 + m * 16 + (lane & 15);
        int c = (kk * 4 + (lane >> 4)) ^ (row & 7);
        a[m][kk] = *(const f16x8*)&As[cur][row * 64 + c * 8];
      }
#pragma unroll
    for (int n = 0; n < 2; n++)
#pragma unroll
      for (int kk = 0; kk < 2; kk++) {
        int row = wc * 32 + n * 16 + (lane & 15);
        int c = (kk * 4 + (lane >> 4)) ^ (row & 7);
        bgf[n][kk] = *(const f16x8*)&Bg[cur][row * 64 + c * 8];
      }
    if (t >= 1 && t < 15) stAh1(t + 1);
    SB; BAR; LGKM0;
    __builtin_amdgcn_s_setprio(1);
#pragma unroll
    for (int kk = 0; kk < 2; kk++)
#pragma unroll
      for (int m = 0; m < 4; m++)
#pragma unroll
        for (int n = 0; n < 2; n++)
          accg[m][n] = MFMA16(a[m][kk], bgf[n][kk], accg[m][n]);
    __builtin_amdgcn_s_setprio(0);
    SB; BAR;
    // ======== P1: reads bu; stage Bg(t+2); MFMA u-low ========
#pragma unroll
    for (int n = 0; n < 2; n++)
#pragma unroll
      for (int kk = 0; kk < 2; kk++) {
        int row = wc * 32 + n * 16 + (lane & 15);
        int c = (kk * 4 + (lane >> 4)) ^ (row & 7);
        buf_[n][kk] = *(const f16x8*)&Bu[cur][row * 64 + c * 8];
      }
    if (t < 14) stBg(t + 2);
    SB; BAR; LGKM0;
    __builtin_amdgcn_s_setprio(1);
#pragma unroll
    for (int kk = 0; kk < 2; kk++)
#pragma unroll
      for (int m = 0; m < 4; m++)
#pragma unroll
        for (int n = 0; n < 2; n++)
          accu[m][n] = MFMA16(a[m][kk], buf_[n][kk], accu[m][n]);
    __builtin_amdgcn_s_setprio(0);
    SB; BAR;
    // ======== P2: reads a4-7; stage Bu(t+2); MFMA g-high ========
#pragma unroll
    for (int m = 0; m < 4; m++)
#pragma unroll
      for (int kk = 0; kk < 2; kk++) {
        int row = wr * 128 + (m + 4) * 16 + (lane & 15);
        int c = (kk * 4 + (lane >> 4)) ^ (row & 7);
        a[m][kk] = *(const f16x8*)&As[cur][row * 64 + c * 8];
      }
    if (t < 14) stBu(t + 2);
    SB; BAR; LGKM0;
    __builtin_amdgcn_s_setprio(1);
#pragma unroll
    for (int kk = 0; kk < 2; kk++)
#pragma unroll
      for (int m = 0; m < 4; m++)
#pragma unroll
        for (int n = 0; n < 2; n++)
          accg[m + 4][n] = MFMA16(a[m][kk], bgf[n][kk], accg[m + 4][n]);
    __builtin_amdgcn_s_setprio(0);
    SB; BAR;
    // ======== P3: stage Ah0(t+2); MFMA u-high; counted vmcnt ========
    if (t < 14) stAh0(t + 2);
    SB; BAR; LGKM0;
    __builtin_amdgcn_s_setprio(1);
#pragma unroll
    for (int kk = 0; kk < 2; kk++)
#pragma unroll
      for (int m = 0; m < 4; m++)
#pragma unroll
        for (int n = 0; n < 2; n++)
          accu[m + 4][n] = MFMA16(a[m][kk], buf_[n][kk], accu[m + 4][n]);
    __builtin_amdgcn_s_setprio(0);
    SB;
    if (t < 14) asm volatile("s_waitcnt vmcnt(6)" ::: "memory");
    else        asm volatile("s_waitcnt vmcnt(0)" ::: "memory");
    SB; BAR;
  }

  int rbase = e * CAP + rb * 256 + wr * 128;
  int cbase = cb * 128 + wc * 32;
#pragma unroll
  for (int m = 0; m < 8; m++)
#pragma unroll
    for (int n = 0; n < 2; n++)
#pragma unroll
      for (int rr = 0; rr < 4; rr++) {
        int row = rbase + m * 16 + (lane >> 4) * 4 + rr;
        int col = cbase + n * 16 + (lane & 15);
        float g = accg[m][n][rr];
        float u = accu[m][n][rr];
        float s = g / (1.f + __expf(-g));
        GU[(size_t)row * ID + col] = (f16)(s * u);
      }
}

// ---------------- GEMM2: GU @ wd^T -> OE fp16 ----------------
// BM=256 x BN=256 x BK=64; 8 waves (2m x 4n), per-wave 128x64.
// Stage ledger: Bh1(t+1)@P0, Ah1(t+1)@P1, Bh0(t+2)@P2, Ah0(t+2)@P3; vmcnt(4)@P3.
__global__ __launch_bounds__(512, 2) void gemm2_kernel(
    const f16* __restrict__ GU, const f16* __restrict__ WDh,
    const int* __restrict__ mrows, f16* __restrict__ OE) {
  __shared__ __align__(16) f16 As[2][256 * 64];   // 64 KB
  __shared__ __align__(16) f16 Bs[2][256 * 64];   // 64 KB

  int bid = ((int)blockIdx.x & 7) * 80 + ((int)blockIdx.x >> 3);  // XCD swizzle (640 = 8*80)
  int e = bid / 40;
  int r = bid % 40;
  int rb = r / 4, cb = r % 4;
  if (rb * 256 >= mrows[e]) return;

  int tid = threadIdx.x;
  int wave = tid >> 6, lane = tid & 63;
  int wr = wave >> 2, wc = wave & 3;   // 2 x 4

  const f16* aS[4];
  const f16* bS[4];
  int sO[4];
#pragma unroll
  for (int j = 0; j < 4; j++) {
    int o = j * 512 + tid;
    int row = o >> 3, ch = o & 7;
    int sw = (ch ^ (row & 7)) * 8;
    aS[j] = GU + (size_t)(e * CAP + rb * 256 + row) * ID + sw;
    bS[j] = WDh + (size_t)e * HD * ID + (size_t)(cb * 256 + row) * ID + sw;
    sO[j] = o * 8;
  }

  auto stAh0 = [&](int tile) { int bf = tile & 1, kh = tile * 64;
    async16(&As[bf][sO[0]], aS[0] + kh); async16(&As[bf][sO[1]], aS[1] + kh); };
  auto stAh1 = [&](int tile) { int bf = tile & 1, kh = tile * 64;
    async16(&As[bf][sO[2]], aS[2] + kh); async16(&As[bf][sO[3]], aS[3] + kh); };
  auto stBh0 = [&](int tile) { int bf = tile & 1, kh = tile * 64;
    async16(&Bs[bf][sO[0]], bS[0] + kh); async16(&Bs[bf][sO[1]], bS[1] + kh); };
  auto stBh1 = [&](int tile) { int bf = tile & 1, kh = tile * 64;
    async16(&Bs[bf][sO[2]], bS[2] + kh); async16(&Bs[bf][sO[3]], bS[3] + kh); };

  stBh0(0); stBh1(0); stAh0(0); stAh1(0);
  stBh0(1); stBh1(1); stAh0(1); stAh1(1);
  asm volatile("s_waitcnt vmcnt(8)" ::: "memory");
  SB; BAR; SB;

  f32x4 acc[8][4] = {};
  f16x8 a[4][2], b[4][2];

  for (int t = 0; t < 16; t++) {
    int cur = t & 1;
    // ======== P0: reads a0-3 + b0-1; stage Bh1(t+1); MFMA m-low x n-low ========
#pragma unroll
    for (int m = 0; m < 4; m++)
#pragma unroll
      for (int kk = 0; kk < 2; kk++) {
        int row = wr * 128 + m * 16 + (lane & 15);
        int c = (kk * 4 + (lane >> 4)) ^ (row & 7);
        a[m][kk] = *(const f16x8*)&As[cur][row * 64 + c * 8];
      }
#pragma unroll
    for (int n = 0; n < 2; n++)
#pragma unroll
      for (int kk = 0; kk < 2; kk++) {
        int row = wc * 64 + n * 16 + (lane & 15);
        int c = (kk * 4 + (lane >> 4)) ^ (row & 7);
        b[n][kk] = *(const f16x8*)&Bs[cur][row * 64 + c * 8];
      }
    if (t >= 1 && t < 15) stBh1(t + 1);
    SB; BAR; LGKM0;
    __builtin_amdgcn_s_setprio(1);
#pragma unroll
    for (int kk = 0; kk < 2; kk++)
#pragma unroll
      for (int m = 0; m < 4; m++)
#pragma unroll
        for (int n = 0; n < 2; n++)
          acc[m][n] = MFMA16(a[m][kk], b[n][kk], acc[m][n]);
    __builtin_amdgcn_s_setprio(0);
    SB; BAR;
    // ======== P1: reads b2-3; stage Ah1(t+1); MFMA m-low x n-high ========
#pragma unroll
    for (int n = 0; n < 2; n++)
#pragma unroll
      for (int kk = 0; kk < 2; kk++) {
        int row = wc * 64 + (n + 2) * 16 + (lane & 15);
        int c = (kk * 4 + (lane >> 4)) ^ (row & 7);
        b[n + 2][kk] = *(const f16x8*)&Bs[cur][row * 64 + c * 8];
      }
    if (t >= 1 && t < 15) stAh1(t + 1);
    SB; BAR; LGKM0;
    __builtin_amdgcn_s_setprio(1);
#pragma unroll
    for (int kk = 0; kk < 2; kk++)
#pragma unroll
      for (int m = 0; m < 4; m++)
#pragma unroll
        for (int n = 0; n < 2; n++)
          acc[m][n + 2] = MFMA16(a[m][kk], b[n + 2][kk], acc[m][n + 2]);
    __builtin_amdgcn_s_setprio(0);
    SB; BAR;
    // ======== P2: reads a4-7; stage Bh0(t+2); MFMA m-high x n-low ========
#pragma unroll
    for (int m = 0; m < 4; m++)
#pragma unroll
      for (int kk = 0; kk < 2; kk++) {
        int row = wr * 128 + (m + 4) * 16 + (lane & 15);
        int c = (kk * 4 + (lane >> 4)) ^ (row & 7);
        a[m][kk] = *(const f16x8*)&As[cur][row * 64 + c * 8];
      }
    if (t < 14) stBh0(t + 2);
    SB; BAR; LGKM0;
    __builtin_amdgcn_s_setprio(1);
#pragma unroll
    for (int kk = 0; kk < 2; kk++)
#pragma unroll
      for (int m = 0; m < 4; m++)
#pragma unroll
        for (int n = 0; n < 2; n++)
          acc[m + 4][n] = MFMA16(a[m][kk], b[n][kk], acc[m + 4][n]);
    __builtin_amdgcn_s_setprio(0);
    SB; BAR;
    // ======== P3: stage Ah0(t+2); MFMA m-high x n-high; counted vmcnt ========
    if (t < 14) stAh0(t + 2);
    SB; BAR; LGKM0;
    __builtin_amdgcn_s_setprio(1);
#pragma unroll
    for (int kk = 0; kk < 2; kk++)
#pragma unroll
      for (int m = 0; m < 4; m++)
#pragma unroll
        for (int n = 0; n < 2; n++)
          acc[m + 4][n + 2] = MFMA16(a[m][kk], b[n + 2][kk], acc[m + 4][n + 2]);
    __builtin_amdgcn_s_setprio(0);
    SB;
    if (t < 14) asm volatile("s_waitcnt vmcnt(4)" ::: "memory");
    else        asm volatile("s_waitcnt vmcnt(0)" ::: "memory");
    SB; BAR;
  }

  int rbase = e * CAP + rb * 256 + wr * 128;
  int cbase = cb * 256 + wc * 64;
#pragma unroll
  for (int m = 0; m < 8; m++)
#pragma unroll
    for (int n = 0; n < 4; n++)
#pragma unroll
      for (int rr = 0; rr < 4; rr++) {
        int row = rbase + m * 16 + (lane >> 4) * 4 + rr;
        int col = cbase + n * 16 + (lane & 15);
        OE[(size_t)row * HD + col] = (f16)acc[m][n][rr];
      }
}

// ---------------- combine: out[t] = sum_k w_k * OE[slot_k] ----------------
__global__ void combine_kernel(const f16* __restrict__ OE, const int* __restrict__ tokSlot,
                               const float* __restrict__ tokW, float* __restrict__ out) {
  int t = blockIdx.x, tid = threadIdx.x;
  int s0 = tokSlot[t * 2], s1 = tokSlot[t * 2 + 1];
  float w0 = tokW[t * 2], w1 = tokW[t * 2 + 1];
  int c = tid * 4;
  float4 o = {0.f, 0.f, 0.f, 0.f};
  if (s0 >= 0) {
    f16x4 v = *(const f16x4*)&OE[(size_t)s0 * HD + c];
    o.x += w0 * (float)v[0]; o.y += w0 * (float)v[1];
    o.z += w0 * (float)v[2]; o.w += w0 * (float)v[3];
  }
  if (s1 >= 0) {
    f16x4 v = *(const f16x4*)&OE[(size_t)s1 * HD + c];
    o.x += w1 * (float)v[0]; o.y += w1 * (float)v[1];
    o.z += w1 * (float)v[2]; o.w += w1 * (float)v[3];
  }
  *(float4*)&out[(size_t)t * HD + c] = o;
  if (t == 0 && tid == 0) out[(size_t)N_TOK * HD] = 0.f;  // aux_loss
}

extern "C" void kernel_launch(void* const* d_in, const int* in_sizes, int n_in,
                              void* d_out, int out_size, void* d_ws, size_t ws_size,
                              hipStream_t stream) {
  (void)in_sizes; (void)n_in; (void)out_size; (void)ws_size;
  const float* x  = (const float*)d_in[0];
  const float* gw = (const float*)d_in[1];
  const float* wg = (const float*)d_in[2];
  const float* wu = (const float*)d_in[3];
  const float* wd = (const float*)d_in[4];
  float* out = (float*)d_out;

  char* ws = (char*)d_ws;
  f16* Xh  = (f16*)ws;                          // 32 MB
  f16* WGh = (f16*)(ws + 33554432ll);           // 32 MB
  f16* WUh = (f16*)(ws + 67108864ll);           // 32 MB
  f16* WDh = (f16*)(ws + 100663296ll);          // 32 MB
  f16* GU  = (f16*)(ws + 134217728ll);          // 80 MB
  f16* OE  = (f16*)ws;                          // aliases Xh/WGh (dead by GEMM2)
  char* rt = ws + 218103808ll;
  int*   cnt     = (int*)rt;                    // 64 B
  int*   mrows   = (int*)(rt + 64);             // 64 B
  int*   rowTok  = (int*)(rt + 128);            // 160 KB
  int*   tokSlot = (int*)(rt + 128 + 163840);   // 128 KB
  float* tokW    = (float*)(rt + 128 + 163840 + 131072);
  char*  rb      = rt + 128 + 163840 + 131072 + 131072;
  int*   bTok  = (int*)rb;                      // 2 MB
  float* bW    = (float*)(rb + 2097152);        // 2 MB
  int*   bFlat = (int*)(rb + 4194304);          // 2 MB
  int*   tokE  = (int*)(rb + 6291456);          // 128 KB

  cvt3_kernel<<<4096, 256, 0, stream>>>(wg, wu, wd, WGh, WUh, WDh, NE * ID * HD / 4);
  gate_kernel<<<N_TOK / 4, 256, 0, stream>>>(x, gw, tokE, tokW, Xh);
  bucket_kernel<<<NE, 1024, 0, stream>>>(tokE, tokW, cnt, bTok, bW, bFlat);
  rank_kernel<<<NE, 256, 0, stream>>>(cnt, mrows, bTok, bW, bFlat, rowTok, tokSlot);
  gemm1_kernel<<<NE * 10 * 8, 512, 0, stream>>>(Xh, WGh, WUh, rowTok, mrows, GU);
  gemm2_kernel<<<NE * 10 * 4, 512, 0, stream>>>(GU, WDh, mrows, OE);
  combine_kernel<<<N_TOK, 256, 0, stream>>>(OE, tokSlot, tokW, out);
}

// Round 6
// 434.495 us; speedup vs baseline: 1.1670x; 1.0563x over previous
//
#include <hip/hip_runtime.h>

#define N_TOK 16384
#define HD 1024
#define ID 1024
#define NE 16
#define CAP 2560
#define NKA 32768   // N_TOK * K assignments
#define SEG 8192    // NKA / 4 bucket segments

typedef _Float16 f16;
typedef _Float16 f16x4 __attribute__((ext_vector_type(4)));
typedef _Float16 f16x8 __attribute__((ext_vector_type(8)));
typedef float f32x4 __attribute__((ext_vector_type(4)));

#define MFMA16(a, b, c) __builtin_amdgcn_mfma_f32_16x16x32_f16(a, b, c, 0, 0, 0)
#define SB __builtin_amdgcn_sched_barrier(0)
#define BAR __builtin_amdgcn_s_barrier()
#define LGKM0 do { asm volatile("s_waitcnt lgkmcnt(0)" ::: "memory"); SB; } while (0)

__device__ __forceinline__ void async16(f16* lds, const f16* g) {
  __builtin_amdgcn_global_load_lds(
      (const __attribute__((address_space(1))) unsigned int*)g,
      (__attribute__((address_space(3))) unsigned int*)lds, 16, 0, 0);
}

// ---------------- fused: gating (blocks 0..4095) + weight fp32->fp16 cvt (blocks 4096..7167) ----------------
__global__ void gate_cvt_kernel(const float* __restrict__ x, const float* __restrict__ gw,
                                const float* __restrict__ wg, const float* __restrict__ wu,
                                const float* __restrict__ wd,
                                int* __restrict__ tokE, float* __restrict__ tokW,
                                f16* __restrict__ Xh, f16* __restrict__ WGh,
                                f16* __restrict__ WUh, f16* __restrict__ WDh) {
  if (blockIdx.x >= 4096) {
    // weight conversion part: 3072 blocks, grid-stride over 4M float4 per tensor
    int start = (blockIdx.x - 4096) * 256 + threadIdx.x;
    const int stride = 3072 * 256;
    const int n4 = NE * ID * HD / 4;
    for (int i = start; i < n4; i += stride) {
      float4 v = ((const float4*)wg)[i];
      f16x4 h = {(f16)v.x, (f16)v.y, (f16)v.z, (f16)v.w};
      ((f16x4*)WGh)[i] = h;
    }
    for (int i = start; i < n4; i += stride) {
      float4 v = ((const float4*)wu)[i];
      f16x4 h = {(f16)v.x, (f16)v.y, (f16)v.z, (f16)v.w};
      ((f16x4*)WUh)[i] = h;
    }
    for (int i = start; i < n4; i += stride) {
      float4 v = ((const float4*)wd)[i];
      f16x4 h = {(f16)v.x, (f16)v.y, (f16)v.z, (f16)v.w};
      ((f16x4*)WDh)[i] = h;
    }
    return;
  }
  // gating part: one token per wave, 4 waves/block
  int t = blockIdx.x * 4 + (threadIdx.x >> 6);
  int lane = threadIdx.x & 63;
  const float4* xr = (const float4*)(x + (size_t)t * HD);
  const float4* gr = (const float4*)gw;
  f16x4* xw = (f16x4*)(Xh + (size_t)t * HD);
  float acc[NE];
#pragma unroll
  for (int e = 0; e < NE; e++) acc[e] = 0.f;
  for (int j = lane; j < HD / 4; j += 64) {
    float4 xv = xr[j];
    f16x4 h = {(f16)xv.x, (f16)xv.y, (f16)xv.z, (f16)xv.w};
    xw[j] = h;
#pragma unroll
    for (int e = 0; e < NE; e++) {
      float4 gv = gr[e * (HD / 4) + j];
      acc[e] += xv.x * gv.x + xv.y * gv.y + xv.z * gv.z + xv.w * gv.w;
    }
  }
#pragma unroll
  for (int e = 0; e < NE; e++) {
#pragma unroll
    for (int off = 32; off > 0; off >>= 1) acc[e] += __shfl_xor(acc[e], off);
  }
  if (lane == 0) {
    int i0 = 0;
#pragma unroll
    for (int e = 1; e < NE; e++) if (acc[e] > acc[i0]) i0 = e;
    int i1 = (i0 == 0) ? 1 : 0;
#pragma unroll
    for (int e = 0; e < NE; e++) if (e != i0 && acc[e] > acc[i1]) i1 = e;
    float mx = fmaxf(acc[i0], acc[i1]);
    float p0 = __expf(acc[i0] - mx), p1 = __expf(acc[i1] - mx);
    float inv = 1.f / (p0 + p1);
    tokE[t * 2] = i0;
    tokE[t * 2 + 1] = i1;
    tokW[t * 2] = p0 * inv;
    tokW[t * 2 + 1] = p1 * inv;
  }
}

// ---------------- bucket: ballot-compaction, 64 blocks = (expert, quarter-segment) ----------------
__global__ __launch_bounds__(1024) void bucket_kernel(
    const int* __restrict__ tokE, const float* __restrict__ tokW,
    int* __restrict__ cntq, int* __restrict__ bTok, float* __restrict__ bW,
    int* __restrict__ bFlat) {
  int e = blockIdx.x >> 2, q = blockIdx.x & 3;
  int tid = threadIdx.x;  // 1024 = 16 waves
  int wid = tid >> 6, lane = tid & 63;
  __shared__ int wsum[16];
  __shared__ int wbase[16];
  __shared__ int chunkTotal;
  int base = q * SEG;
  int total = 0;
  for (int c = 0; c < SEG; c += 1024) {
    int a = base + c + tid;
    bool pred = (tokE[a] == e);
    unsigned long long mask = __ballot(pred);
    int myrank = __popcll(mask & ((1ull << lane) - 1ull));
    if (lane == 0) wsum[wid] = __popcll(mask);
    __syncthreads();
    if (tid == 0) {
      int s = 0;
#pragma unroll
      for (int w = 0; w < 16; w++) { wbase[w] = s; s += wsum[w]; }
      chunkTotal = s;
    }
    __syncthreads();
    if (pred) {
      int pos = base + total + wbase[wid] + myrank;  // compacted within this segment
      bTok[e * NKA + pos] = a >> 1;
      bW[e * NKA + pos] = tokW[a];
      bFlat[e * NKA + pos] = a;
    }
    total += chunkTotal;
    __syncthreads();
  }
  if (tid == 0) cntq[e * 4 + q] = total;
}

// ---------------- rank: capacity selection over 4 gapped segments (order = flat asc) ----------------
__global__ void rank_kernel(const int* __restrict__ cntq, int* __restrict__ mrows,
                            const int* __restrict__ bTok, const float* __restrict__ bW,
                            const int* __restrict__ bFlat, int* __restrict__ rowTok,
                            int* __restrict__ tokSlot) {
  int e = blockIdx.x, tid = threadIdx.x;
  int cq[4], off[4];
  int c = 0;
#pragma unroll
  for (int q = 0; q < 4; q++) { cq[q] = cntq[e * 4 + q]; off[q] = c; c += cq[q]; }
  int m = c < CAP ? c : CAP;
  if (tid == 0) mrows[e] = m;
  if (c <= CAP) {
#pragma unroll
    for (int q = 0; q < 4; q++)
      for (int i = tid; i < cq[q]; i += blockDim.x) {
        int src = e * NKA + q * SEG + i;
        int slot = e * CAP + off[q] + i;
        rowTok[slot] = bTok[src];
        tokSlot[bFlat[src]] = slot;
      }
  } else {
    for (int q = 0; q < 4; q++)
      for (int i = tid; i < cq[q]; i += blockDim.x) {
        int src = e * NKA + q * SEG + i;
        float wp = bW[src];
        int fp = bFlat[src];
        int rank = 0;
        for (int q2 = 0; q2 < 4; q2++)
          for (int j = 0; j < cq[q2]; j++) {
            int s2 = e * NKA + q2 * SEG + j;
            float wq = bW[s2];
            rank += (wq > wp) || (wq == wp && bFlat[s2] < fp);
          }
        if (rank < CAP) {
          int slot = e * CAP + rank;
          rowTok[slot] = bTok[src];
          tokSlot[fp] = slot;
        } else {
          tokSlot[fp] = -1;
        }
      }
  }
}

// ---------------- GEMM1: gathered X @ {wg,wu}^T, fused silu*u -> GU fp16 ----------------
// BM=256 x (128 g + 128 u) x BK=64; 8 waves (2m x 4n), per-wave 128x(32g+32u).
// 4 phases/K-tile: {quadrant ds_reads; 1 half-tile stage} -> BAR -> lgkm0 -> 16 MFMA -> BAR.
// Stage ledger: Ah1(t+1)@P0, Bg(t+2)@P1, Bu(t+2)@P2, Ah0(t+2)@P3; vmcnt(6)@P3.
__global__ __launch_bounds__(512, 2) void gemm1_kernel(
    const f16* __restrict__ Xh, const f16* __restrict__ WGh, const f16* __restrict__ WUh,
    const int* __restrict__ rowTok, const int* __restrict__ mrows, f16* __restrict__ GU) {
  __shared__ __align__(16) f16 As[2][256 * 64];   // 64 KB
  __shared__ __align__(16) f16 Bg[2][128 * 64];   // 32 KB
  __shared__ __align__(16) f16 Bu[2][128 * 64];   // 32 KB

  int bid = ((int)blockIdx.x & 7) * 160 + ((int)blockIdx.x >> 3);  // XCD swizzle (1280 = 8*160)
  int e = bid / 80;
  int r = bid % 80;
  int rb = r / 8, cb = r % 8;
  int me = mrows[e];
  if (rb * 256 >= me) return;

  int tid = threadIdx.x;
  int wave = tid >> 6, lane = tid & 63;
  int wr = wave >> 2, wc = wave & 3;   // 2 x 4

  const f16* aS[4];
  int aO[4];
#pragma unroll
  for (int j = 0; j < 4; j++) {
    int o = j * 512 + tid;
    int row = o >> 3, ch = o & 7;
    int rg = rb * 256 + row;
    int tok = (rg < me) ? rowTok[e * CAP + rg] : 0;
    aS[j] = Xh + (size_t)tok * HD + ((ch ^ (row & 7)) * 8);
    aO[j] = o * 8;
  }
  const f16* gS[2];
  const f16* uS[2];
  int bO[2];
#pragma unroll
  for (int j = 0; j < 2; j++) {
    int o = j * 512 + tid;
    int row = o >> 3, ch = o & 7;
    size_t w = (size_t)e * ID * HD + (size_t)(cb * 128 + row) * HD + ((ch ^ (row & 7)) * 8);
    gS[j] = WGh + w;
    uS[j] = WUh + w;
    bO[j] = o * 8;
  }

  auto stAh0 = [&](int tile) { int bf = tile & 1, kh = tile * 64;
    async16(&As[bf][aO[0]], aS[0] + kh); async16(&As[bf][aO[1]], aS[1] + kh); };
  auto stAh1 = [&](int tile) { int bf = tile & 1, kh = tile * 64;
    async16(&As[bf][aO[2]], aS[2] + kh); async16(&As[bf][aO[3]], aS[3] + kh); };
  auto stBg = [&](int tile) { int bf = tile & 1, kh = tile * 64;
    async16(&Bg[bf][bO[0]], gS[0] + kh); async16(&Bg[bf][bO[1]], gS[1] + kh); };
  auto stBu = [&](int tile) { int bf = tile & 1, kh = tile * 64;
    async16(&Bu[bf][bO[0]], uS[0] + kh); async16(&Bu[bf][bO[1]], uS[1] + kh); };

  stBg(0); stBu(0); stAh0(0); stAh1(0);
  stBg(1); stBu(1); stAh0(1); stAh1(1);
  asm volatile("s_waitcnt vmcnt(8)" ::: "memory");
  SB; BAR; SB;

  f32x4 accg[8][2] = {};
  f32x4 accu[8][2] = {};
  f16x8 a[4][2], bgf[2][2], buf_[2][2];

  for (int t = 0; t < 16; t++) {
    int cur = t & 1;
    // ======== P0: reads a0-3 + bg; stage Ah1(t+1); MFMA g-low ========
#pragma unroll
    for (int m = 0; m < 4; m++)
#pragma unroll
      for (int kk = 0; kk < 2; kk++) {
        int row = wr * 128 + m * 16 + (lane & 15);
        int c = (kk * 4 + (lane >> 4)) ^ (row & 7);
        a[m][kk] = *(const f16x8*)&As[cur][row * 64 + c * 8];
      }
#pragma unroll
    for (int n = 0; n < 2; n++)
#pragma unroll
      for (int kk = 0; kk < 2; kk++) {
        int row = wc * 32 + n * 16 + (lane & 15);
        int c = (kk * 4 + (lane >> 4)) ^ (row & 7);
        bgf[n][kk] = *(const f16x8*)&Bg[cur][row * 64 + c * 8];
      }
    if (t >= 1 && t < 15) stAh1(t + 1);
    SB; BAR; LGKM0;
    __builtin_amdgcn_s_setprio(1);
#pragma unroll
    for (int kk = 0; kk < 2; kk++)
#pragma unroll
      for (int m = 0; m < 4; m++)
#pragma unroll
        for (int n = 0; n < 2; n++)
          accg[m][n] = MFMA16(a[m][kk], bgf[n][kk], accg[m][n]);
    __builtin_amdgcn_s_setprio(0);
    SB; BAR;
    // ======== P1: reads bu; stage Bg(t+2); MFMA u-low ========
#pragma unroll
    for (int n = 0; n < 2; n++)
#pragma unroll
      for (int kk = 0; kk < 2; kk++) {
        int row = wc * 32 + n * 16 + (lane & 15);
        int c = (kk * 4 + (lane >> 4)) ^ (row & 7);
        buf_[n][kk] = *(const f16x8*)&Bu[cur][row * 64 + c * 8];
      }
    if (t < 14) stBg(t + 2);
    SB; BAR; LGKM0;
    __builtin_amdgcn_s_setprio(1);
#pragma unroll
    for (int kk = 0; kk < 2; kk++)
#pragma unroll
      for (int m = 0; m < 4; m++)
#pragma unroll
        for (int n = 0; n < 2; n++)
          accu[m][n] = MFMA16(a[m][kk], buf_[n][kk], accu[m][n]);
    __builtin_amdgcn_s_setprio(0);
    SB; BAR;
    // ======== P2: reads a4-7; stage Bu(t+2); MFMA g-high ========
#pragma unroll
    for (int m = 0; m < 4; m++)
#pragma unroll
      for (int kk = 0; kk < 2; kk++) {
        int row = wr * 128 + (m + 4) * 16 + (lane & 15);
        int c = (kk * 4 + (lane >> 4)) ^ (row & 7);
        a[m][kk] = *(const f16x8*)&As[cur][row * 64 + c * 8];
      }
    if (t < 14) stBu(t + 2);
    SB; BAR; LGKM0;
    __builtin_amdgcn_s_setprio(1);
#pragma unroll
    for (int kk = 0; kk < 2; kk++)
#pragma unroll
      for (int m = 0; m < 4; m++)
#pragma unroll
        for (int n = 0; n < 2; n++)
          accg[m + 4][n] = MFMA16(a[m][kk], bgf[n][kk], accg[m + 4][n]);
    __builtin_amdgcn_s_setprio(0);
    SB; BAR;
    // ======== P3: stage Ah0(t+2); MFMA u-high; counted vmcnt ========
    if (t < 14) stAh0(t + 2);
    SB; BAR; LGKM0;
    __builtin_amdgcn_s_setprio(1);
#pragma unroll
    for (int kk = 0; kk < 2; kk++)
#pragma unroll
      for (int m = 0; m < 4; m++)
#pragma unroll
        for (int n = 0; n < 2; n++)
          accu[m + 4][n] = MFMA16(a[m][kk], buf_[n][kk], accu[m + 4][n]);
    __builtin_amdgcn_s_setprio(0);
    SB;
    if (t < 14) asm volatile("s_waitcnt vmcnt(6)" ::: "memory");
    else        asm volatile("s_waitcnt vmcnt(0)" ::: "memory");
    SB; BAR;
  }

  int rbase = e * CAP + rb * 256 + wr * 128;
  int cbase = cb * 128 + wc * 32;
#pragma unroll
  for (int m = 0; m < 8; m++)
#pragma unroll
    for (int n = 0; n < 2; n++)
#pragma unroll
      for (int rr = 0; rr < 4; rr++) {
        int row = rbase + m * 16 + (lane >> 4) * 4 + rr;
        int col = cbase + n * 16 + (lane & 15);
        float g = accg[m][n][rr];
        float u = accu[m][n][rr];
        float s = g / (1.f + __expf(-g));
        GU[(size_t)row * ID + col] = (f16)(s * u);
      }
}

// ---------------- GEMM2: GU @ wd^T -> OE fp16 ----------------
// BM=256 x BN=256 x BK=64; 8 waves (2m x 4n), per-wave 128x64.
// Stage ledger: Bh1(t+1)@P0, Ah1(t+1)@P1, Bh0(t+2)@P2, Ah0(t+2)@P3; vmcnt(4)@P3.
__global__ __launch_bounds__(512, 2) void gemm2_kernel(
    const f16* __restrict__ GU, const f16* __restrict__ WDh,
    const int* __restrict__ mrows, f16* __restrict__ OE) {
  __shared__ __align__(16) f16 As[2][256 * 64];   // 64 KB
  __shared__ __align__(16) f16 Bs[2][256 * 64];   // 64 KB

  int bid = ((int)blockIdx.x & 7) * 80 + ((int)blockIdx.x >> 3);  // XCD swizzle (640 = 8*80)
  int e = bid / 40;
  int r = bid % 40;
  int rb = r / 4, cb = r % 4;
  if (rb * 256 >= mrows[e]) return;

  int tid = threadIdx.x;
  int wave = tid >> 6, lane = tid & 63;
  int wr = wave >> 2, wc = wave & 3;   // 2 x 4

  const f16* aS[4];
  const f16* bS[4];
  int sO[4];
#pragma unroll
  for (int j = 0; j < 4; j++) {
    int o = j * 512 + tid;
    int row = o >> 3, ch = o & 7;
    int sw = (ch ^ (row & 7)) * 8;
    aS[j] = GU + (size_t)(e * CAP + rb * 256 + row) * ID + sw;
    bS[j] = WDh + (size_t)e * HD * ID + (size_t)(cb * 256 + row) * ID + sw;
    sO[j] = o * 8;
  }

  auto stAh0 = [&](int tile) { int bf = tile & 1, kh = tile * 64;
    async16(&As[bf][sO[0]], aS[0] + kh); async16(&As[bf][sO[1]], aS[1] + kh); };
  auto stAh1 = [&](int tile) { int bf = tile & 1, kh = tile * 64;
    async16(&As[bf][sO[2]], aS[2] + kh); async16(&As[bf][sO[3]], aS[3] + kh); };
  auto stBh0 = [&](int tile) { int bf = tile & 1, kh = tile * 64;
    async16(&Bs[bf][sO[0]], bS[0] + kh); async16(&Bs[bf][sO[1]], bS[1] + kh); };
  auto stBh1 = [&](int tile) { int bf = tile & 1, kh = tile * 64;
    async16(&Bs[bf][sO[2]], bS[2] + kh); async16(&Bs[bf][sO[3]], bS[3] + kh); };

  stBh0(0); stBh1(0); stAh0(0); stAh1(0);
  stBh0(1); stBh1(1); stAh0(1); stAh1(1);
  asm volatile("s_waitcnt vmcnt(8)" ::: "memory");
  SB; BAR; SB;

  f32x4 acc[8][4] = {};
  f16x8 a[4][2], b[4][2];

  for (int t = 0; t < 16; t++) {
    int cur = t & 1;
    // ======== P0 ========
#pragma unroll
    for (int m = 0; m < 4; m++)
#pragma unroll
      for (int kk = 0; kk < 2; kk++) {
        int row = wr * 128 + m * 16 + (lane & 15);
        int c = (kk * 4 + (lane >> 4)) ^ (row & 7);
        a[m][kk] = *(const f16x8*)&As[cur][row * 64 + c * 8];
      }
#pragma unroll
    for (int n = 0; n < 2; n++)
#pragma unroll
      for (int kk = 0; kk < 2; kk++) {
        int row = wc * 64 + n * 16 + (lane & 15);
        int c = (kk * 4 + (lane >> 4)) ^ (row & 7);
        b[n][kk] = *(const f16x8*)&Bs[cur][row * 64 + c * 8];
      }
    if (t >= 1 && t < 15) stBh1(t + 1);
    SB; BAR; LGKM0;
    __builtin_amdgcn_s_setprio(1);
#pragma unroll
    for (int kk = 0; kk < 2; kk++)
#pragma unroll
      for (int m = 0; m < 4; m++)
#pragma unroll
        for (int n = 0; n < 2; n++)
          acc[m][n] = MFMA16(a[m][kk], b[n][kk], acc[m][n]);
    __builtin_amdgcn_s_setprio(0);
    SB; BAR;
    // ======== P1 ========
#pragma unroll
    for (int n = 0; n < 2; n++)
#pragma unroll
      for (int kk = 0; kk < 2; kk++) {
        int row = wc * 64 + (n + 2) * 16 + (lane & 15);
        int c = (kk * 4 + (lane >> 4)) ^ (row & 7);
        b[n + 2][kk] = *(const f16x8*)&Bs[cur][row * 64 + c * 8];
      }
    if (t >= 1 && t < 15) stAh1(t + 1);
    SB; BAR; LGKM0;
    __builtin_amdgcn_s_setprio(1);
#pragma unroll
    for (int kk = 0; kk < 2; kk++)
#pragma unroll
      for (int m = 0; m < 4; m++)
#pragma unroll
        for (int n = 0; n < 2; n++)
          acc[m][n + 2] = MFMA16(a[m][kk], b[n + 2][kk], acc[m][n + 2]);
    __builtin_amdgcn_s_setprio(0);
    SB; BAR;
    // ======== P2 ========
#pragma unroll
    for (int m = 0; m < 4; m++)
#pragma unroll
      for (int kk = 0; kk < 2; kk++) {
        int row = wr * 128 + (m + 4) * 16 + (lane & 15);
        int c = (kk * 4 + (lane >> 4)) ^ (row & 7);
        a[m][kk] = *(const f16x8*)&As[cur][row * 64 + c * 8];
      }
    if (t < 14) stBh0(t + 2);
    SB; BAR; LGKM0;
    __builtin_amdgcn_s_setprio(1);
#pragma unroll
    for (int kk = 0; kk < 2; kk++)
#pragma unroll
      for (int m = 0; m < 4; m++)
#pragma unroll
        for (int n = 0; n < 2; n++)
          acc[m + 4][n] = MFMA16(a[m][kk], b[n][kk], acc[m + 4][n]);
    __builtin_amdgcn_s_setprio(0);
    SB; BAR;
    // ======== P3 ========
    if (t < 14) stAh0(t + 2);
    SB; BAR; LGKM0;
    __builtin_amdgcn_s_setprio(1);
#pragma unroll
    for (int kk = 0; kk < 2; kk++)
#pragma unroll
      for (int m = 0; m < 4; m++)
#pragma unroll
        for (int n = 0; n < 2; n++)
          acc[m + 4][n + 2] = MFMA16(a[m][kk], b[n + 2][kk], acc[m + 4][n + 2]);
    __builtin_amdgcn_s_setprio(0);
    SB;
    if (t < 14) asm volatile("s_waitcnt vmcnt(4)" ::: "memory");
    else        asm volatile("s_waitcnt vmcnt(0)" ::: "memory");
    SB; BAR;
  }

  int rbase = e * CAP + rb * 256 + wr * 128;
  int cbase = cb * 256 + wc * 64;
#pragma unroll
  for (int m = 0; m < 8; m++)
#pragma unroll
    for (int n = 0; n < 4; n++)
#pragma unroll
      for (int rr = 0; rr < 4; rr++) {
        int row = rbase + m * 16 + (lane >> 4) * 4 + rr;
        int col = cbase + n * 16 + (lane & 15);
        OE[(size_t)row * HD + col] = (f16)acc[m][n][rr];
      }
}

// ---------------- combine: out[t] = sum_k w_k * OE[slot_k] (128 thr, 8 cols each) ----------------
__global__ void combine_kernel(const f16* __restrict__ OE, const int* __restrict__ tokSlot,
                               const float* __restrict__ tokW, float* __restrict__ out) {
  int t = blockIdx.x, tid = threadIdx.x;
  int s0 = tokSlot[t * 2], s1 = tokSlot[t * 2 + 1];
  float w0 = tokW[t * 2], w1 = tokW[t * 2 + 1];
  int c = tid * 8;
  float o[8] = {};
  if (s0 >= 0) {
    f16x8 v = *(const f16x8*)&OE[(size_t)s0 * HD + c];
#pragma unroll
    for (int j = 0; j < 8; j++) o[j] += w0 * (float)v[j];
  }
  if (s1 >= 0) {
    f16x8 v = *(const f16x8*)&OE[(size_t)s1 * HD + c];
#pragma unroll
    for (int j = 0; j < 8; j++) o[j] += w1 * (float)v[j];
  }
  float4 lo = {o[0], o[1], o[2], o[3]}, hi = {o[4], o[5], o[6], o[7]};
  *(float4*)&out[(size_t)t * HD + c] = lo;
  *(float4*)&out[(size_t)t * HD + c + 4] = hi;
  if (t == 0 && tid == 0) out[(size_t)N_TOK * HD] = 0.f;  // aux_loss
}

extern "C" void kernel_launch(void* const* d_in, const int* in_sizes, int n_in,
                              void* d_out, int out_size, void* d_ws, size_t ws_size,
                              hipStream_t stream) {
  (void)in_sizes; (void)n_in; (void)out_size; (void)ws_size;
  const float* x  = (const float*)d_in[0];
  const float* gw = (const float*)d_in[1];
  const float* wg = (const float*)d_in[2];
  const float* wu = (const float*)d_in[3];
  const float* wd = (const float*)d_in[4];
  float* out = (float*)d_out;

  char* ws = (char*)d_ws;
  f16* Xh  = (f16*)ws;                          // 32 MB
  f16* WGh = (f16*)(ws + 33554432ll);           // 32 MB
  f16* WUh = (f16*)(ws + 67108864ll);           // 32 MB
  f16* WDh = (f16*)(ws + 100663296ll);          // 32 MB
  f16* GU  = (f16*)(ws + 134217728ll);          // 80 MB
  f16* OE  = (f16*)ws;                          // aliases Xh/WGh (dead by GEMM2)
  char* rt = ws + 218103808ll;
  int*   cntq    = (int*)rt;                    // 256 B (16 experts x 4 segments)
  int*   mrows   = (int*)(rt + 256);            // 64 B
  int*   rowTok  = (int*)(rt + 512);            // 160 KB
  int*   tokSlot = (int*)(rt + 512 + 163840);   // 128 KB
  float* tokW    = (float*)(rt + 512 + 163840 + 131072);
  char*  rb      = rt + 512 + 163840 + 131072 + 131072;
  int*   bTok  = (int*)rb;                      // 2 MB
  float* bW    = (float*)(rb + 2097152);        // 2 MB
  int*   bFlat = (int*)(rb + 4194304);          // 2 MB
  int*   tokE  = (int*)(rb + 6291456);          // 128 KB

  gate_cvt_kernel<<<7168, 256, 0, stream>>>(x, gw, wg, wu, wd, tokE, tokW, Xh, WGh, WUh, WDh);
  bucket_kernel<<<64, 1024, 0, stream>>>(tokE, tokW, cntq, bTok, bW, bFlat);
  rank_kernel<<<NE, 256, 0, stream>>>(cntq, mrows, bTok, bW, bFlat, rowTok, tokSlot);
  gemm1_kernel<<<NE * 10 * 8, 512, 0, stream>>>(Xh, WGh, WUh, rowTok, mrows, GU);
  gemm2_kernel<<<NE * 10 * 4, 512, 0, stream>>>(GU, WDh, mrows, OE);
  combine_kernel<<<N_TOK, 128, 0, stream>>>(OE, tokSlot, tokW, out);
}

// Round 7
// 419.358 us; speedup vs baseline: 1.2091x; 1.0361x over previous
//
#include <hip/hip_runtime.h>

#define N_TOK 16384
#define HD 1024
#define ID 1024
#define NE 16
#define CAP 2560
#define NKA 32768   // N_TOK * K assignments
#define SEG 8192    // NKA / 4 bucket segments

typedef _Float16 f16;
typedef _Float16 f16x4 __attribute__((ext_vector_type(4)));
typedef _Float16 f16x8 __attribute__((ext_vector_type(8)));
typedef float f32x4 __attribute__((ext_vector_type(4)));

#define MFMA16(a, b, c) __builtin_amdgcn_mfma_f32_16x16x32_f16(a, b, c, 0, 0, 0)
#define SB __builtin_amdgcn_sched_barrier(0)
#define BAR __builtin_amdgcn_s_barrier()
#define LGKM0 do { asm volatile("s_waitcnt lgkmcnt(0)" ::: "memory"); SB; } while (0)

__device__ __forceinline__ void async16(f16* lds, const f16* g) {
  __builtin_amdgcn_global_load_lds(
      (const __attribute__((address_space(1))) unsigned int*)g,
      (__attribute__((address_space(3))) unsigned int*)lds, 16, 0, 0);
}

// ---------------- gating: logits, softmax, top-2; emits Xh (fp16 x) ----------------
__global__ void gate_kernel(const float* __restrict__ x, const float* __restrict__ gw,
                            int* __restrict__ tokE, float* __restrict__ tokW,
                            f16* __restrict__ Xh) {
  int t = blockIdx.x * 4 + (threadIdx.x >> 6);
  int lane = threadIdx.x & 63;
  const float4* xr = (const float4*)(x + (size_t)t * HD);
  const float4* gr = (const float4*)gw;
  f16x4* xw = (f16x4*)(Xh + (size_t)t * HD);
  float acc[NE];
#pragma unroll
  for (int e = 0; e < NE; e++) acc[e] = 0.f;
  for (int j = lane; j < HD / 4; j += 64) {
    float4 xv = xr[j];
    f16x4 h = {(f16)xv.x, (f16)xv.y, (f16)xv.z, (f16)xv.w};
    xw[j] = h;
#pragma unroll
    for (int e = 0; e < NE; e++) {
      float4 gv = gr[e * (HD / 4) + j];
      acc[e] += xv.x * gv.x + xv.y * gv.y + xv.z * gv.z + xv.w * gv.w;
    }
  }
#pragma unroll
  for (int e = 0; e < NE; e++) {
#pragma unroll
    for (int off = 32; off > 0; off >>= 1) acc[e] += __shfl_xor(acc[e], off);
  }
  if (lane == 0) {
    int i0 = 0;
#pragma unroll
    for (int e = 1; e < NE; e++) if (acc[e] > acc[i0]) i0 = e;
    int i1 = (i0 == 0) ? 1 : 0;
#pragma unroll
    for (int e = 0; e < NE; e++) if (e != i0 && acc[e] > acc[i1]) i1 = e;
    float mx = fmaxf(acc[i0], acc[i1]);
    float p0 = __expf(acc[i0] - mx), p1 = __expf(acc[i1] - mx);
    float inv = 1.f / (p0 + p1);
    tokE[t * 2] = i0;
    tokE[t * 2 + 1] = i1;
    tokW[t * 2] = p0 * inv;
    tokW[t * 2 + 1] = p1 * inv;
  }
}

// ---------------- bucket (blocks 0..63) + wg/wu fp32->fp16 cvt (blocks 64..2111) ----------------
__global__ __launch_bounds__(1024) void bucketcvt_kernel(
    const int* __restrict__ tokE, const float* __restrict__ tokW,
    int* __restrict__ cntq, int* __restrict__ bTok, float* __restrict__ bW,
    int* __restrict__ bFlat,
    const float* __restrict__ wg, const float* __restrict__ wu,
    f16* __restrict__ WGh, f16* __restrict__ WUh) {
  if (blockIdx.x >= 64) {
    int start = ((int)blockIdx.x - 64) * 1024 + (int)threadIdx.x;
    const int stride = 2048 * 1024;
    const int n4 = NE * ID * HD / 4;
    for (int i = start; i < n4; i += stride) {
      float4 v = ((const float4*)wg)[i];
      f16x4 h = {(f16)v.x, (f16)v.y, (f16)v.z, (f16)v.w};
      ((f16x4*)WGh)[i] = h;
    }
    for (int i = start; i < n4; i += stride) {
      float4 v = ((const float4*)wu)[i];
      f16x4 h = {(f16)v.x, (f16)v.y, (f16)v.z, (f16)v.w};
      ((f16x4*)WUh)[i] = h;
    }
    return;
  }
  int e = blockIdx.x >> 2, q = blockIdx.x & 3;
  int tid = threadIdx.x;  // 1024 = 16 waves
  int wid = tid >> 6, lane = tid & 63;
  __shared__ int wsum[16];
  __shared__ int wbase[16];
  __shared__ int chunkTotal;
  int base = q * SEG;
  int total = 0;
  for (int c = 0; c < SEG; c += 1024) {
    int a = base + c + tid;
    bool pred = (tokE[a] == e);
    unsigned long long mask = __ballot(pred);
    int myrank = __popcll(mask & ((1ull << lane) - 1ull));
    if (lane == 0) wsum[wid] = __popcll(mask);
    __syncthreads();
    if (tid == 0) {
      int s = 0;
#pragma unroll
      for (int w = 0; w < 16; w++) { wbase[w] = s; s += wsum[w]; }
      chunkTotal = s;
    }
    __syncthreads();
    if (pred) {
      int pos = base + total + wbase[wid] + myrank;  // compacted within this segment
      bTok[e * NKA + pos] = a >> 1;
      bW[e * NKA + pos] = tokW[a];
      bFlat[e * NKA + pos] = a;
    }
    total += chunkTotal;
    __syncthreads();
  }
  if (tid == 0) cntq[e * 4 + q] = total;
}

// ---------------- rank: capacity selection over 4 gapped segments (order = flat asc) ----------------
__global__ void rank_kernel(const int* __restrict__ cntq, int* __restrict__ mrows,
                            const int* __restrict__ bTok, const float* __restrict__ bW,
                            const int* __restrict__ bFlat, int* __restrict__ rowTok,
                            int* __restrict__ tokSlot) {
  int e = blockIdx.x, tid = threadIdx.x;
  int cq[4], off[4];
  int c = 0;
#pragma unroll
  for (int q = 0; q < 4; q++) { cq[q] = cntq[e * 4 + q]; off[q] = c; c += cq[q]; }
  int m = c < CAP ? c : CAP;
  if (tid == 0) mrows[e] = m;
  if (c <= CAP) {
#pragma unroll
    for (int q = 0; q < 4; q++)
      for (int i = tid; i < cq[q]; i += blockDim.x) {
        int src = e * NKA + q * SEG + i;
        int slot = e * CAP + off[q] + i;
        rowTok[slot] = bTok[src];
        tokSlot[bFlat[src]] = slot;
      }
  } else {
    for (int q = 0; q < 4; q++)
      for (int i = tid; i < cq[q]; i += blockDim.x) {
        int src = e * NKA + q * SEG + i;
        float wp = bW[src];
        int fp = bFlat[src];
        int rank = 0;
        for (int q2 = 0; q2 < 4; q2++)
          for (int j = 0; j < cq[q2]; j++) {
            int s2 = e * NKA + q2 * SEG + j;
            float wq = bW[s2];
            rank += (wq > wp) || (wq == wp && bFlat[s2] < fp);
          }
        if (rank < CAP) {
          int slot = e * CAP + rank;
          rowTok[slot] = bTok[src];
          tokSlot[fp] = slot;
        } else {
          tokSlot[fp] = -1;
        }
      }
  }
}

// ---------------- GEMM1 (blocks 0..1279) + wd cvt tail (blocks 1280..2303) ----------------
// BM=256 x (128 g + 128 u) x BK=64; 8 waves (2m x 4n), per-wave 128x(32g+32u).
// 4 phases/K-tile: {quadrant ds_reads; 1 half-tile stage} -> BAR -> lgkm0 -> 16 MFMA -> BAR.
// Stage ledger: Ah1(t+1)@P0, Bg(t+2)@P1, Bu(t+2)@P2, Ah0(t+2)@P3; vmcnt(6)@P3.
__global__ __launch_bounds__(512, 2) void gemm1_kernel(
    const f16* __restrict__ Xh, const f16* __restrict__ WGh, const f16* __restrict__ WUh,
    const int* __restrict__ rowTok, const int* __restrict__ mrows, f16* __restrict__ GU,
    const float* __restrict__ wd, f16* __restrict__ WDh) {
  __shared__ __align__(16) f16 As[2][256 * 64];   // 64 KB
  __shared__ __align__(16) f16 Bg[2][128 * 64];   // 32 KB
  __shared__ __align__(16) f16 Bu[2][128 * 64];   // 32 KB

  if (blockIdx.x >= 1280) {
    // wd fp32->fp16 conversion, fills gemm1's tail rounds (gemm2 consumes WDh next launch)
    int start = ((int)blockIdx.x - 1280) * 512 + (int)threadIdx.x;
    const int stride = 1024 * 512;
    const int n4 = NE * HD * ID / 4;
    for (int i = start; i < n4; i += stride) {
      float4 v = ((const float4*)wd)[i];
      f16x4 h = {(f16)v.x, (f16)v.y, (f16)v.z, (f16)v.w};
      ((f16x4*)WDh)[i] = h;
    }
    return;
  }

  int bid = ((int)blockIdx.x & 7) * 160 + ((int)blockIdx.x >> 3);  // XCD swizzle (1280 = 8*160)
  int e = bid / 80;
  int r = bid % 80;
  int rb = r / 8, cb = r % 8;
  int me = mrows[e];
  if (rb * 256 >= me) return;

  int tid = threadIdx.x;
  int wave = tid >> 6, lane = tid & 63;
  int wr = wave >> 2, wc = wave & 3;   // 2 x 4

  const f16* aS[4];
  int aO[4];
#pragma unroll
  for (int j = 0; j < 4; j++) {
    int o = j * 512 + tid;
    int row = o >> 3, ch = o & 7;
    int rg = rb * 256 + row;
    int tok = (rg < me) ? rowTok[e * CAP + rg] : 0;
    aS[j] = Xh + (size_t)tok * HD + ((ch ^ (row & 7)) * 8);
    aO[j] = o * 8;
  }
  const f16* gS[2];
  const f16* uS[2];
  int bO[2];
#pragma unroll
  for (int j = 0; j < 2; j++) {
    int o = j * 512 + tid;
    int row = o >> 3, ch = o & 7;
    size_t w = (size_t)e * ID * HD + (size_t)(cb * 128 + row) * HD + ((ch ^ (row & 7)) * 8);
    gS[j] = WGh + w;
    uS[j] = WUh + w;
    bO[j] = o * 8;
  }

  auto stAh0 = [&](int tile) { int bf = tile & 1, kh = tile * 64;
    async16(&As[bf][aO[0]], aS[0] + kh); async16(&As[bf][aO[1]], aS[1] + kh); };
  auto stAh1 = [&](int tile) { int bf = tile & 1, kh = tile * 64;
    async16(&As[bf][aO[2]], aS[2] + kh); async16(&As[bf][aO[3]], aS[3] + kh); };
  auto stBg = [&](int tile) { int bf = tile & 1, kh = tile * 64;
    async16(&Bg[bf][bO[0]], gS[0] + kh); async16(&Bg[bf][bO[1]], gS[1] + kh); };
  auto stBu = [&](int tile) { int bf = tile & 1, kh = tile * 64;
    async16(&Bu[bf][bO[0]], uS[0] + kh); async16(&Bu[bf][bO[1]], uS[1] + kh); };

  stBg(0); stBu(0); stAh0(0); stAh1(0);
  stBg(1); stBu(1); stAh0(1); stAh1(1);
  asm volatile("s_waitcnt vmcnt(8)" ::: "memory");
  SB; BAR; SB;

  f32x4 accg[8][2] = {};
  f32x4 accu[8][2] = {};
  f16x8 a[4][2], bgf[2][2], buf_[2][2];

  for (int t = 0; t < 16; t++) {
    int cur = t & 1;
    // ======== P0: reads a0-3 + bg; stage Ah1(t+1); MFMA g-low ========
#pragma unroll
    for (int m = 0; m < 4; m++)
#pragma unroll
      for (int kk = 0; kk < 2; kk++) {
        int row = wr * 128 + m * 16 + (lane & 15);
        int c = (kk * 4 + (lane >> 4)) ^ (row & 7);
        a[m][kk] = *(const f16x8*)&As[cur][row * 64 + c * 8];
      }
#pragma unroll
    for (int n = 0; n < 2; n++)
#pragma unroll
      for (int kk = 0; kk < 2; kk++) {
        int row = wc * 32 + n * 16 + (lane & 15);
        int c = (kk * 4 + (lane >> 4)) ^ (row & 7);
        bgf[n][kk] = *(const f16x8*)&Bg[cur][row * 64 + c * 8];
      }
    if (t >= 1 && t < 15) stAh1(t + 1);
    SB; BAR; LGKM0;
    __builtin_amdgcn_s_setprio(1);
#pragma unroll
    for (int kk = 0; kk < 2; kk++)
#pragma unroll
      for (int m = 0; m < 4; m++)
#pragma unroll
        for (int n = 0; n < 2; n++)
          accg[m][n] = MFMA16(a[m][kk], bgf[n][kk], accg[m][n]);
    __builtin_amdgcn_s_setprio(0);
    SB; BAR;
    // ======== P1: reads bu; stage Bg(t+2); MFMA u-low ========
#pragma unroll
    for (int n = 0; n < 2; n++)
#pragma unroll
      for (int kk = 0; kk < 2; kk++) {
        int row = wc * 32 + n * 16 + (lane & 15);
        int c = (kk * 4 + (lane >> 4)) ^ (row & 7);
        buf_[n][kk] = *(const f16x8*)&Bu[cur][row * 64 + c * 8];
      }
    if (t < 14) stBg(t + 2);
    SB; BAR; LGKM0;
    __builtin_amdgcn_s_setprio(1);
#pragma unroll
    for (int kk = 0; kk < 2; kk++)
#pragma unroll
      for (int m = 0; m < 4; m++)
#pragma unroll
        for (int n = 0; n < 2; n++)
          accu[m][n] = MFMA16(a[m][kk], buf_[n][kk], accu[m][n]);
    __builtin_amdgcn_s_setprio(0);
    SB; BAR;
    // ======== P2: reads a4-7; stage Bu(t+2); MFMA g-high ========
#pragma unroll
    for (int m = 0; m < 4; m++)
#pragma unroll
      for (int kk = 0; kk < 2; kk++) {
        int row = wr * 128 + (m + 4) * 16 + (lane & 15);
        int c = (kk * 4 + (lane >> 4)) ^ (row & 7);
        a[m][kk] = *(const f16x8*)&As[cur][row * 64 + c * 8];
      }
    if (t < 14) stBu(t + 2);
    SB; BAR; LGKM0;
    __builtin_amdgcn_s_setprio(1);
#pragma unroll
    for (int kk = 0; kk < 2; kk++)
#pragma unroll
      for (int m = 0; m < 4; m++)
#pragma unroll
        for (int n = 0; n < 2; n++)
          accg[m + 4][n] = MFMA16(a[m][kk], bgf[n][kk], accg[m + 4][n]);
    __builtin_amdgcn_s_setprio(0);
    SB; BAR;
    // ======== P3: stage Ah0(t+2); MFMA u-high; counted vmcnt ========
    if (t < 14) stAh0(t + 2);
    SB; BAR; LGKM0;
    __builtin_amdgcn_s_setprio(1);
#pragma unroll
    for (int kk = 0; kk < 2; kk++)
#pragma unroll
      for (int m = 0; m < 4; m++)
#pragma unroll
        for (int n = 0; n < 2; n++)
          accu[m + 4][n] = MFMA16(a[m][kk], buf_[n][kk], accu[m + 4][n]);
    __builtin_amdgcn_s_setprio(0);
    SB;
    if (t < 14) asm volatile("s_waitcnt vmcnt(6)" ::: "memory");
    else        asm volatile("s_waitcnt vmcnt(0)" ::: "memory");
    SB; BAR;
  }

  int rbase = e * CAP + rb * 256 + wr * 128;
  int cbase = cb * 128 + wc * 32;
#pragma unroll
  for (int m = 0; m < 8; m++)
#pragma unroll
    for (int n = 0; n < 2; n++)
#pragma unroll
      for (int rr = 0; rr < 4; rr++) {
        int row = rbase + m * 16 + (lane >> 4) * 4 + rr;
        int col = cbase + n * 16 + (lane & 15);
        float g = accg[m][n][rr];
        float u = accu[m][n][rr];
        float s = g / (1.f + __expf(-g));
        GU[(size_t)row * ID + col] = (f16)(s * u);
      }
}

// ---------------- GEMM2: GU @ wd^T -> OE fp16 ----------------
// BM=256 x BN=256 x BK=64; 8 waves (2m x 4n), per-wave 128x64.
// Stage ledger: Bh1(t+1)@P0, Ah1(t+1)@P1, Bh0(t+2)@P2, Ah0(t+2)@P3; vmcnt(4)@P3.
__global__ __launch_bounds__(512, 2) void gemm2_kernel(
    const f16* __restrict__ GU, const f16* __restrict__ WDh,
    const int* __restrict__ mrows, f16* __restrict__ OE) {
  __shared__ __align__(16) f16 As[2][256 * 64];   // 64 KB
  __shared__ __align__(16) f16 Bs[2][256 * 64];   // 64 KB

  int bid = ((int)blockIdx.x & 7) * 80 + ((int)blockIdx.x >> 3);  // XCD swizzle (640 = 8*80)
  int e = bid / 40;
  int r = bid % 40;
  int rb = r / 4, cb = r % 4;
  if (rb * 256 >= mrows[e]) return;

  int tid = threadIdx.x;
  int wave = tid >> 6, lane = tid & 63;
  int wr = wave >> 2, wc = wave & 3;   // 2 x 4

  const f16* aS[4];
  const f16* bS[4];
  int sO[4];
#pragma unroll
  for (int j = 0; j < 4; j++) {
    int o = j * 512 + tid;
    int row = o >> 3, ch = o & 7;
    int sw = (ch ^ (row & 7)) * 8;
    aS[j] = GU + (size_t)(e * CAP + rb * 256 + row) * ID + sw;
    bS[j] = WDh + (size_t)e * HD * ID + (size_t)(cb * 256 + row) * ID + sw;
    sO[j] = o * 8;
  }

  auto stAh0 = [&](int tile) { int bf = tile & 1, kh = tile * 64;
    async16(&As[bf][sO[0]], aS[0] + kh); async16(&As[bf][sO[1]], aS[1] + kh); };
  auto stAh1 = [&](int tile) { int bf = tile & 1, kh = tile * 64;
    async16(&As[bf][sO[2]], aS[2] + kh); async16(&As[bf][sO[3]], aS[3] + kh); };
  auto stBh0 = [&](int tile) { int bf = tile & 1, kh = tile * 64;
    async16(&Bs[bf][sO[0]], bS[0] + kh); async16(&Bs[bf][sO[1]], bS[1] + kh); };
  auto stBh1 = [&](int tile) { int bf = tile & 1, kh = tile * 64;
    async16(&Bs[bf][sO[2]], bS[2] + kh); async16(&Bs[bf][sO[3]], bS[3] + kh); };

  stBh0(0); stBh1(0); stAh0(0); stAh1(0);
  stBh0(1); stBh1(1); stAh0(1); stAh1(1);
  asm volatile("s_waitcnt vmcnt(8)" ::: "memory");
  SB; BAR; SB;

  f32x4 acc[8][4] = {};
  f16x8 a[4][2], b[4][2];

  for (int t = 0; t < 16; t++) {
    int cur = t & 1;
    // ======== P0 ========
#pragma unroll
    for (int m = 0; m < 4; m++)
#pragma unroll
      for (int kk = 0; kk < 2; kk++) {
        int row = wr * 128 + m * 16 + (lane & 15);
        int c = (kk * 4 + (lane >> 4)) ^ (row & 7);
        a[m][kk] = *(const f16x8*)&As[cur][row * 64 + c * 8];
      }
#pragma unroll
    for (int n = 0; n < 2; n++)
#pragma unroll
      for (int kk = 0; kk < 2; kk++) {
        int row = wc * 64 + n * 16 + (lane & 15);
        int c = (kk * 4 + (lane >> 4)) ^ (row & 7);
        b[n][kk] = *(const f16x8*)&Bs[cur][row * 64 + c * 8];
      }
    if (t >= 1 && t < 15) stBh1(t + 1);
    SB; BAR; LGKM0;
    __builtin_amdgcn_s_setprio(1);
#pragma unroll
    for (int kk = 0; kk < 2; kk++)
#pragma unroll
      for (int m = 0; m < 4; m++)
#pragma unroll
        for (int n = 0; n < 2; n++)
          acc[m][n] = MFMA16(a[m][kk], b[n][kk], acc[m][n]);
    __builtin_amdgcn_s_setprio(0);
    SB; BAR;
    // ======== P1 ========
#pragma unroll
    for (int n = 0; n < 2; n++)
#pragma unroll
      for (int kk = 0; kk < 2; kk++) {
        int row = wc * 64 + (n + 2) * 16 + (lane & 15);
        int c = (kk * 4 + (lane >> 4)) ^ (row & 7);
        b[n + 2][kk] = *(const f16x8*)&Bs[cur][row * 64 + c * 8];
      }
    if (t >= 1 && t < 15) stAh1(t + 1);
    SB; BAR; LGKM0;
    __builtin_amdgcn_s_setprio(1);
#pragma unroll
    for (int kk = 0; kk < 2; kk++)
#pragma unroll
      for (int m = 0; m < 4; m++)
#pragma unroll
        for (int n = 0; n < 2; n++)
          acc[m][n + 2] = MFMA16(a[m][kk], b[n + 2][kk], acc[m][n + 2]);
    __builtin_amdgcn_s_setprio(0);
    SB; BAR;
    // ======== P2 ========
#pragma unroll
    for (int m = 0; m < 4; m++)
#pragma unroll
      for (int kk = 0; kk < 2; kk++) {
        int row = wr * 128 + (m + 4) * 16 + (lane & 15);
        int c = (kk * 4 + (lane >> 4)) ^ (row & 7);
        a[m][kk] = *(const f16x8*)&As[cur][row * 64 + c * 8];
      }
    if (t < 14) stBh0(t + 2);
    SB; BAR; LGKM0;
    __builtin_amdgcn_s_setprio(1);
#pragma unroll
    for (int kk = 0; kk < 2; kk++)
#pragma unroll
      for (int m = 0; m < 4; m++)
#pragma unroll
        for (int n = 0; n < 2; n++)
          acc[m + 4][n] = MFMA16(a[m][kk], b[n][kk], acc[m + 4][n]);
    __builtin_amdgcn_s_setprio(0);
    SB; BAR;
    // ======== P3 ========
    if (t < 14) stAh0(t + 2);
    SB; BAR; LGKM0;
    __builtin_amdgcn_s_setprio(1);
#pragma unroll
    for (int kk = 0; kk < 2; kk++)
#pragma unroll
      for (int m = 0; m < 4; m++)
#pragma unroll
        for (int n = 0; n < 2; n++)
          acc[m + 4][n + 2] = MFMA16(a[m][kk], b[n + 2][kk], acc[m + 4][n + 2]);
    __builtin_amdgcn_s_setprio(0);
    SB;
    if (t < 14) asm volatile("s_waitcnt vmcnt(4)" ::: "memory");
    else        asm volatile("s_waitcnt vmcnt(0)" ::: "memory");
    SB; BAR;
  }

  int rbase = e * CAP + rb * 256 + wr * 128;
  int cbase = cb * 256 + wc * 64;
#pragma unroll
  for (int m = 0; m < 8; m++)
#pragma unroll
    for (int n = 0; n < 4; n++)
#pragma unroll
      for (int rr = 0; rr < 4; rr++) {
        int row = rbase + m * 16 + (lane >> 4) * 4 + rr;
        int col = cbase + n * 16 + (lane & 15);
        OE[(size_t)row * HD + col] = (f16)acc[m][n][rr];
      }
}

// ---------------- combine: out[t] = sum_k w_k * OE[slot_k] (128 thr, 8 cols each) ----------------
__global__ void combine_kernel(const f16* __restrict__ OE, const int* __restrict__ tokSlot,
                               const float* __restrict__ tokW, float* __restrict__ out) {
  int t = blockIdx.x, tid = threadIdx.x;
  int s0 = tokSlot[t * 2], s1 = tokSlot[t * 2 + 1];
  float w0 = tokW[t * 2], w1 = tokW[t * 2 + 1];
  int c = tid * 8;
  float o[8] = {};
  if (s0 >= 0) {
    f16x8 v = *(const f16x8*)&OE[(size_t)s0 * HD + c];
#pragma unroll
    for (int j = 0; j < 8; j++) o[j] += w0 * (float)v[j];
  }
  if (s1 >= 0) {
    f16x8 v = *(const f16x8*)&OE[(size_t)s1 * HD + c];
#pragma unroll
    for (int j = 0; j < 8; j++) o[j] += w1 * (float)v[j];
  }
  float4 lo = {o[0], o[1], o[2], o[3]}, hi = {o[4], o[5], o[6], o[7]};
  *(float4*)&out[(size_t)t * HD + c] = lo;
  *(float4*)&out[(size_t)t * HD + c + 4] = hi;
  if (t == 0 && tid == 0) out[(size_t)N_TOK * HD] = 0.f;  // aux_loss
}

extern "C" void kernel_launch(void* const* d_in, const int* in_sizes, int n_in,
                              void* d_out, int out_size, void* d_ws, size_t ws_size,
                              hipStream_t stream) {
  (void)in_sizes; (void)n_in; (void)out_size; (void)ws_size;
  const float* x  = (const float*)d_in[0];
  const float* gw = (const float*)d_in[1];
  const float* wg = (const float*)d_in[2];
  const float* wu = (const float*)d_in[3];
  const float* wd = (const float*)d_in[4];
  float* out = (float*)d_out;

  char* ws = (char*)d_ws;
  f16* Xh  = (f16*)ws;                          // 32 MB
  f16* WGh = (f16*)(ws + 33554432ll);           // 32 MB
  f16* WUh = (f16*)(ws + 67108864ll);           // 32 MB
  f16* WDh = (f16*)(ws + 100663296ll);          // 32 MB
  f16* GU  = (f16*)(ws + 134217728ll);          // 80 MB
  f16* OE  = (f16*)ws;                          // aliases Xh/WGh (dead by GEMM2)
  char* rt = ws + 218103808ll;
  int*   cntq    = (int*)rt;                    // 256 B (16 experts x 4 segments)
  int*   mrows   = (int*)(rt + 256);            // 64 B
  int*   rowTok  = (int*)(rt + 512);            // 160 KB
  int*   tokSlot = (int*)(rt + 512 + 163840);   // 128 KB
  float* tokW    = (float*)(rt + 512 + 163840 + 131072);
  char*  rb      = rt + 512 + 163840 + 131072 + 131072;
  int*   bTok  = (int*)rb;                      // 2 MB
  float* bW    = (float*)(rb + 2097152);        // 2 MB
  int*   bFlat = (int*)(rb + 4194304);          // 2 MB
  int*   tokE  = (int*)(rb + 6291456);          // 128 KB

  gate_kernel<<<N_TOK / 4, 256, 0, stream>>>(x, gw, tokE, tokW, Xh);
  bucketcvt_kernel<<<64 + 2048, 1024, 0, stream>>>(tokE, tokW, cntq, bTok, bW, bFlat,
                                                   wg, wu, WGh, WUh);
  rank_kernel<<<NE, 256, 0, stream>>>(cntq, mrows, bTok, bW, bFlat, rowTok, tokSlot);
  gemm1_kernel<<<1280 + 1024, 512, 0, stream>>>(Xh, WGh, WUh, rowTok, mrows, GU, wd, WDh);
  gemm2_kernel<<<NE * 10 * 4, 512, 0, stream>>>(GU, WDh, mrows, OE);
  combine_kernel<<<N_TOK, 128, 0, stream>>>(OE, tokSlot, tokW, out);
}

// Round 8
// 399.939 us; speedup vs baseline: 1.2678x; 1.0486x over previous
//
#include <hip/hip_runtime.h>

#define N_TOK 16384
#define HD 1024
#define ID 1024
#define NE 16
#define CAP 2560
#define NKA 32768   // N_TOK * K assignments
#define SEG 8192    // NKA / 4 bucket segments

typedef _Float16 f16;
typedef _Float16 f16x4 __attribute__((ext_vector_type(4)));
typedef _Float16 f16x8 __attribute__((ext_vector_type(8)));
typedef float f32x4 __attribute__((ext_vector_type(4)));

__device__ __forceinline__ void async16(f16* lds, const f16* g) {
  __builtin_amdgcn_global_load_lds(
      (const __attribute__((address_space(1))) unsigned int*)g,
      (__attribute__((address_space(3))) unsigned int*)lds, 16, 0, 0);
}

// ---------------- gate (blocks 0..4095) + wg/wu fp32->fp16 cvt (blocks 4096..6143) ----------------
__global__ void gate_kernel(const float* __restrict__ x, const float* __restrict__ gw,
                            int* __restrict__ tokE, float* __restrict__ tokW,
                            f16* __restrict__ Xh,
                            const float* __restrict__ wg, const float* __restrict__ wu,
                            f16* __restrict__ WGh, f16* __restrict__ WUh) {
  if (blockIdx.x >= 4096) {
    int start = ((int)blockIdx.x - 4096) * 256 + (int)threadIdx.x;
    const int stride = 2048 * 256;
    const int n4 = NE * ID * HD / 4;
    for (int i = start; i < n4; i += stride) {
      float4 v = ((const float4*)wg)[i];
      f16x4 h = {(f16)v.x, (f16)v.y, (f16)v.z, (f16)v.w};
      ((f16x4*)WGh)[i] = h;
    }
    for (int i = start; i < n4; i += stride) {
      float4 v = ((const float4*)wu)[i];
      f16x4 h = {(f16)v.x, (f16)v.y, (f16)v.z, (f16)v.w};
      ((f16x4*)WUh)[i] = h;
    }
    return;
  }
  int t = blockIdx.x * 4 + (threadIdx.x >> 6);
  int lane = threadIdx.x & 63;
  const float4* xr = (const float4*)(x + (size_t)t * HD);
  const float4* gr = (const float4*)gw;
  f16x4* xw = (f16x4*)(Xh + (size_t)t * HD);
  float acc[NE];
#pragma unroll
  for (int e = 0; e < NE; e++) acc[e] = 0.f;
  for (int j = lane; j < HD / 4; j += 64) {
    float4 xv = xr[j];
    f16x4 h = {(f16)xv.x, (f16)xv.y, (f16)xv.z, (f16)xv.w};
    xw[j] = h;
#pragma unroll
    for (int e = 0; e < NE; e++) {
      float4 gv = gr[e * (HD / 4) + j];
      acc[e] += xv.x * gv.x + xv.y * gv.y + xv.z * gv.z + xv.w * gv.w;
    }
  }
#pragma unroll
  for (int e = 0; e < NE; e++) {
#pragma unroll
    for (int off = 32; off > 0; off >>= 1) acc[e] += __shfl_xor(acc[e], off);
  }
  if (lane == 0) {
    int i0 = 0;
#pragma unroll
    for (int e = 1; e < NE; e++) if (acc[e] > acc[i0]) i0 = e;
    int i1 = (i0 == 0) ? 1 : 0;
#pragma unroll
    for (int e = 0; e < NE; e++) if (e != i0 && acc[e] > acc[i1]) i1 = e;
    float mx = fmaxf(acc[i0], acc[i1]);
    float p0 = __expf(acc[i0] - mx), p1 = __expf(acc[i1] - mx);
    float inv = 1.f / (p0 + p1);
    tokE[t * 2] = i0;
    tokE[t * 2 + 1] = i1;
    tokW[t * 2] = p0 * inv;
    tokW[t * 2 + 1] = p1 * inv;
  }
}

// ---------------- bucket: ballot-compaction, 64 blocks = (expert, quarter-segment) ----------------
__global__ __launch_bounds__(1024) void bucket_kernel(
    const int* __restrict__ tokE, const float* __restrict__ tokW,
    int* __restrict__ cntq, int* __restrict__ bTok, float* __restrict__ bW,
    int* __restrict__ bFlat) {
  int e = blockIdx.x >> 2, q = blockIdx.x & 3;
  int tid = threadIdx.x;  // 1024 = 16 waves
  int wid = tid >> 6, lane = tid & 63;
  __shared__ int wsum[16];
  __shared__ int wbase[16];
  __shared__ int chunkTotal;
  int base = q * SEG;
  int total = 0;
  for (int c = 0; c < SEG; c += 1024) {
    int a = base + c + tid;
    bool pred = (tokE[a] == e);
    unsigned long long mask = __ballot(pred);
    int myrank = __popcll(mask & ((1ull << lane) - 1ull));
    if (lane == 0) wsum[wid] = __popcll(mask);
    __syncthreads();
    if (tid == 0) {
      int s = 0;
#pragma unroll
      for (int w = 0; w < 16; w++) { wbase[w] = s; s += wsum[w]; }
      chunkTotal = s;
    }
    __syncthreads();
    if (pred) {
      int pos = base + total + wbase[wid] + myrank;  // compacted within this segment
      bTok[e * NKA + pos] = a >> 1;
      bW[e * NKA + pos] = tokW[a];
      bFlat[e * NKA + pos] = a;
    }
    total += chunkTotal;
    __syncthreads();
  }
  if (tid == 0) cntq[e * 4 + q] = total;
}

// ---------------- rank: capacity selection over 4 gapped segments (order = flat asc) ----------------
__global__ void rank_kernel(const int* __restrict__ cntq, int* __restrict__ mrows,
                            const int* __restrict__ bTok, const float* __restrict__ bW,
                            const int* __restrict__ bFlat, int* __restrict__ rowTok,
                            int* __restrict__ tokSlot) {
  int e = blockIdx.x, tid = threadIdx.x;
  int cq[4], off[4];
  int c = 0;
#pragma unroll
  for (int q = 0; q < 4; q++) { cq[q] = cntq[e * 4 + q]; off[q] = c; c += cq[q]; }
  int m = c < CAP ? c : CAP;
  if (tid == 0) mrows[e] = m;
  if (c <= CAP) {
#pragma unroll
    for (int q = 0; q < 4; q++)
      for (int i = tid; i < cq[q]; i += blockDim.x) {
        int src = e * NKA + q * SEG + i;
        int slot = e * CAP + off[q] + i;
        rowTok[slot] = bTok[src];
        tokSlot[bFlat[src]] = slot;
      }
  } else {
    for (int q = 0; q < 4; q++)
      for (int i = tid; i < cq[q]; i += blockDim.x) {
        int src = e * NKA + q * SEG + i;
        float wp = bW[src];
        int fp = bFlat[src];
        int rank = 0;
        for (int q2 = 0; q2 < 4; q2++)
          for (int j = 0; j < cq[q2]; j++) {
            int s2 = e * NKA + q2 * SEG + j;
            float wq = bW[s2];
            rank += (wq > wp) || (wq == wp && bFlat[s2] < fp);
          }
        if (rank < CAP) {
          int slot = e * CAP + rank;
          rowTok[slot] = bTok[src];
          tokSlot[fp] = slot;
        } else {
          tokSlot[fp] = -1;
        }
      }
  }
}

// ---------------- GEMM1 (blocks 0..5119) + wd cvt tail (blocks 5120..7167) ----------------
// BM=128 x BN=64(g)+64(u) x BK=64; 4 waves 2x2; counted-vmcnt 2-deep pipeline; 64KB LDS -> 2 blocks/CU
__global__ __launch_bounds__(256, 2) void gemm1_kernel(
    const f16* __restrict__ Xh, const f16* __restrict__ WGh, const f16* __restrict__ WUh,
    const int* __restrict__ rowTok, const int* __restrict__ mrows, f16* __restrict__ GU,
    const float* __restrict__ wd, f16* __restrict__ WDh) {
  __shared__ __align__(16) f16 As[2][128 * 64];
  __shared__ __align__(16) f16 Bg[2][64 * 64];
  __shared__ __align__(16) f16 Bu[2][64 * 64];

  if (blockIdx.x >= 5120) {
    // wd fp32->fp16 conversion, hidden in gemm1's tail (gemm2 consumes WDh next launch)
    int start = ((int)blockIdx.x - 5120) * 256 + (int)threadIdx.x;
    const int stride = 2048 * 256;
    const int n4 = NE * HD * ID / 4;
    for (int i = start; i < n4; i += stride) {
      float4 v = ((const float4*)wd)[i];
      f16x4 h = {(f16)v.x, (f16)v.y, (f16)v.z, (f16)v.w};
      ((f16x4*)WDh)[i] = h;
    }
    return;
  }

  int bid = ((int)blockIdx.x & 7) * 640 + ((int)blockIdx.x >> 3);  // XCD swizzle (5120 = 8*640)
  int e = bid / (20 * 16);
  int r2 = bid % (20 * 16);
  int rb = r2 / 16, cb = r2 % 16;
  int me = mrows[e];
  if (rb * 128 >= me) return;

  int tid = threadIdx.x;
  int wave = tid >> 6, lane = tid & 63;
  int wr = wave >> 1, wc = wave & 1;

  // A staging: 128x64 = 4 issues of (256 threads x 16B); gather rows via rowTok, pre-swizzled src
  const f16* aSrc[4];
  int aOff[4];
#pragma unroll
  for (int j = 0; j < 4; j++) {
    int o = j * 256 + tid;
    int row = o >> 3, ch = o & 7;
    int rg = rb * 128 + row;
    int tok = (rg < me) ? rowTok[e * CAP + rg] : 0;
    aSrc[j] = Xh + (size_t)tok * HD + ((ch ^ (row & 7)) * 8);
    aOff[j] = o * 8;
  }
  // B staging: 64x64 = 2 issues each
  const f16* gS[2];
  const f16* uS[2];
  int bOff[2];
#pragma unroll
  for (int j = 0; j < 2; j++) {
    int o = j * 256 + tid;
    int row = o >> 3, ch = o & 7;
    size_t w = (size_t)e * ID * HD + (size_t)(cb * 64 + row) * HD + ((ch ^ (row & 7)) * 8);
    gS[j] = WGh + w;
    uS[j] = WUh + w;
    bOff[j] = o * 8;
  }

  auto stage = [&](int buf, int kt) {
    int kh = kt * 64;
#pragma unroll
    for (int j = 0; j < 4; j++) async16(&As[buf][aOff[j]], aSrc[j] + kh);
#pragma unroll
    for (int j = 0; j < 2; j++) async16(&Bg[buf][bOff[j]], gS[j] + kh);
#pragma unroll
    for (int j = 0; j < 2; j++) async16(&Bu[buf][bOff[j]], uS[j] + kh);
  };

  stage(0, 0);
  stage(1, 1);

  f32x4 accg[4][2] = {};
  f32x4 accu[4][2] = {};

  for (int t = 0; t < 16; t++) {
    int cur = t & 1;
    if (t < 15) asm volatile("s_waitcnt vmcnt(8)" ::: "memory");
    else        asm volatile("s_waitcnt vmcnt(0)" ::: "memory");
    __builtin_amdgcn_s_barrier();
    __builtin_amdgcn_sched_barrier(0);

    f16x8 a[4][2], bg[2][2], bu[2][2];
#pragma unroll
    for (int m = 0; m < 4; m++)
#pragma unroll
      for (int kk = 0; kk < 2; kk++) {
        int row = wr * 64 + m * 16 + (lane & 15);
        int c = (kk * 4 + (lane >> 4)) ^ (row & 7);
        a[m][kk] = *(const f16x8*)&As[cur][row * 64 + c * 8];
      }
#pragma unroll
    for (int n = 0; n < 2; n++)
#pragma unroll
      for (int kk = 0; kk < 2; kk++) {
        int row = wc * 32 + n * 16 + (lane & 15);
        int c = (kk * 4 + (lane >> 4)) ^ (row & 7);
        bg[n][kk] = *(const f16x8*)&Bg[cur][row * 64 + c * 8];
        bu[n][kk] = *(const f16x8*)&Bu[cur][row * 64 + c * 8];
      }
    asm volatile("s_waitcnt lgkmcnt(0)" ::: "memory");
    __builtin_amdgcn_sched_barrier(0);
    __builtin_amdgcn_s_barrier();

    if (t + 2 < 16) stage(cur, t + 2);
    __builtin_amdgcn_sched_barrier(0);  // keep stage issues ahead of MFMA cluster

#pragma unroll
    for (int kk = 0; kk < 2; kk++)
#pragma unroll
      for (int m = 0; m < 4; m++)
#pragma unroll
        for (int n = 0; n < 2; n++) {
          accg[m][n] = __builtin_amdgcn_mfma_f32_16x16x32_f16(a[m][kk], bg[n][kk], accg[m][n], 0, 0, 0);
          accu[m][n] = __builtin_amdgcn_mfma_f32_16x16x32_f16(a[m][kk], bu[n][kk], accu[m][n], 0, 0, 0);
        }
  }

  int rbase = e * CAP + rb * 128 + wr * 64;
  int cbase = cb * 64 + wc * 32;
#pragma unroll
  for (int m = 0; m < 4; m++)
#pragma unroll
    for (int n = 0; n < 2; n++)
#pragma unroll
      for (int r = 0; r < 4; r++) {
        int row = rbase + m * 16 + (lane >> 4) * 4 + r;
        int col = cbase + n * 16 + (lane & 15);
        float g = accg[m][n][r];
        float u = accu[m][n][r];
        float s = g / (1.f + __expf(-g));
        GU[(size_t)row * ID + col] = (f16)(s * u);
      }
}

// ---------------- GEMM2: GU @ wd^T -> OE fp16 ----------------
// BM=128 x BN=128 x BK=64; 4 waves 2x2; counted-vmcnt 2-deep pipeline; 64KB LDS -> 2 blocks/CU
__global__ __launch_bounds__(256, 2) void gemm2_kernel(
    const f16* __restrict__ GU, const f16* __restrict__ WDh,
    const int* __restrict__ mrows, f16* __restrict__ OE) {
  __shared__ __align__(16) f16 As[2][128 * 64];
  __shared__ __align__(16) f16 Bs[2][128 * 64];

  int bid = ((int)blockIdx.x & 7) * 320 + ((int)blockIdx.x >> 3);  // XCD swizzle (2560 = 8*320)
  int e = bid / (20 * 8);
  int r2 = bid % (20 * 8);
  int rb = r2 / 8, cb = r2 % 8;
  if (rb * 128 >= mrows[e]) return;

  int tid = threadIdx.x;
  int wave = tid >> 6, lane = tid & 63;
  int wr = wave >> 1, wc = wave & 1;

  const f16* aSrc[4];
  const f16* bSrc[4];
  int sOff[4];
#pragma unroll
  for (int j = 0; j < 4; j++) {
    int o = j * 256 + tid;
    int row = o >> 3, ch = o & 7;
    int sw = (ch ^ (row & 7)) * 8;
    aSrc[j] = GU + (size_t)(e * CAP + rb * 128 + row) * ID + sw;
    bSrc[j] = WDh + (size_t)e * HD * ID + (size_t)(cb * 128 + row) * ID + sw;
    sOff[j] = o * 8;
  }

  auto stage = [&](int buf, int kt) {
    int kh = kt * 64;
#pragma unroll
    for (int j = 0; j < 4; j++) async16(&As[buf][sOff[j]], aSrc[j] + kh);
#pragma unroll
    for (int j = 0; j < 4; j++) async16(&Bs[buf][sOff[j]], bSrc[j] + kh);
  };

  stage(0, 0);
  stage(1, 1);

  f32x4 acc[4][4] = {};

  for (int t = 0; t < 16; t++) {
    int cur = t & 1;
    if (t < 15) asm volatile("s_waitcnt vmcnt(8)" ::: "memory");
    else        asm volatile("s_waitcnt vmcnt(0)" ::: "memory");
    __builtin_amdgcn_s_barrier();
    __builtin_amdgcn_sched_barrier(0);

    f16x8 a[4][2], b[4][2];
#pragma unroll
    for (int m = 0; m < 4; m++)
#pragma unroll
      for (int kk = 0; kk < 2; kk++) {
        int row = wr * 64 + m * 16 + (lane & 15);
        int c = (kk * 4 + (lane >> 4)) ^ (row & 7);
        a[m][kk] = *(const f16x8*)&As[cur][row * 64 + c * 8];
      }
#pragma unroll
    for (int n = 0; n < 4; n++)
#pragma unroll
      for (int kk = 0; kk < 2; kk++) {
        int row = wc * 64 + n * 16 + (lane & 15);
        int c = (kk * 4 + (lane >> 4)) ^ (row & 7);
        b[n][kk] = *(const f16x8*)&Bs[cur][row * 64 + c * 8];
      }
    asm volatile("s_waitcnt lgkmcnt(0)" ::: "memory");
    __builtin_amdgcn_sched_barrier(0);
    __builtin_amdgcn_s_barrier();

    if (t + 2 < 16) stage(cur, t + 2);
    __builtin_amdgcn_sched_barrier(0);

#pragma unroll
    for (int kk = 0; kk < 2; kk++)
#pragma unroll
      for (int m = 0; m < 4; m++)
#pragma unroll
        for (int n = 0; n < 4; n++)
          acc[m][n] = __builtin_amdgcn_mfma_f32_16x16x32_f16(a[m][kk], b[n][kk], acc[m][n], 0, 0, 0);
  }

  int rbase = e * CAP + rb * 128 + wr * 64;
  int cbase = cb * 128 + wc * 64;
#pragma unroll
  for (int m = 0; m < 4; m++)
#pragma unroll
    for (int n = 0; n < 4; n++)
#pragma unroll
      for (int r = 0; r < 4; r++) {
        int row = rbase + m * 16 + (lane >> 4) * 4 + r;
        int col = cbase + n * 16 + (lane & 15);
        OE[(size_t)row * HD + col] = (f16)acc[m][n][r];
      }
}

// ---------------- combine: out[t] = sum_k w_k * OE[slot_k] (128 thr, 8 cols each) ----------------
__global__ void combine_kernel(const f16* __restrict__ OE, const int* __restrict__ tokSlot,
                               const float* __restrict__ tokW, float* __restrict__ out) {
  int t = blockIdx.x, tid = threadIdx.x;
  int s0 = tokSlot[t * 2], s1 = tokSlot[t * 2 + 1];
  float w0 = tokW[t * 2], w1 = tokW[t * 2 + 1];
  int c = tid * 8;
  float o[8] = {};
  if (s0 >= 0) {
    f16x8 v = *(const f16x8*)&OE[(size_t)s0 * HD + c];
#pragma unroll
    for (int j = 0; j < 8; j++) o[j] += w0 * (float)v[j];
  }
  if (s1 >= 0) {
    f16x8 v = *(const f16x8*)&OE[(size_t)s1 * HD + c];
#pragma unroll
    for (int j = 0; j < 8; j++) o[j] += w1 * (float)v[j];
  }
  float4 lo = {o[0], o[1], o[2], o[3]}, hi = {o[4], o[5], o[6], o[7]};
  *(float4*)&out[(size_t)t * HD + c] = lo;
  *(float4*)&out[(size_t)t * HD + c + 4] = hi;
  if (t == 0 && tid == 0) out[(size_t)N_TOK * HD] = 0.f;  // aux_loss
}

extern "C" void kernel_launch(void* const* d_in, const int* in_sizes, int n_in,
                              void* d_out, int out_size, void* d_ws, size_t ws_size,
                              hipStream_t stream) {
  (void)in_sizes; (void)n_in; (void)out_size; (void)ws_size;
  const float* x  = (const float*)d_in[0];
  const float* gw = (const float*)d_in[1];
  const float* wg = (const float*)d_in[2];
  const float* wu = (const float*)d_in[3];
  const float* wd = (const float*)d_in[4];
  float* out = (float*)d_out;

  char* ws = (char*)d_ws;
  f16* Xh  = (f16*)ws;                          // 32 MB
  f16* WGh = (f16*)(ws + 33554432ll);           // 32 MB
  f16* WUh = (f16*)(ws + 67108864ll);           // 32 MB
  f16* WDh = (f16*)(ws + 100663296ll);          // 32 MB
  f16* GU  = (f16*)(ws + 134217728ll);          // 80 MB
  f16* OE  = (f16*)ws;                          // aliases Xh/WGh (dead by GEMM2)
  char* rt = ws + 218103808ll;
  int*   cntq    = (int*)rt;                    // 256 B (16 experts x 4 segments)
  int*   mrows   = (int*)(rt + 256);            // 64 B
  int*   rowTok  = (int*)(rt + 512);            // 160 KB
  int*   tokSlot = (int*)(rt + 512 + 163840);   // 128 KB
  float* tokW    = (float*)(rt + 512 + 163840 + 131072);
  char*  rb      = rt + 512 + 163840 + 131072 + 131072;
  int*   bTok  = (int*)rb;                      // 2 MB
  float* bW    = (float*)(rb + 2097152);        // 2 MB
  int*   bFlat = (int*)(rb + 4194304);          // 2 MB
  int*   tokE  = (int*)(rb + 6291456);          // 128 KB

  gate_kernel<<<4096 + 2048, 256, 0, stream>>>(x, gw, tokE, tokW, Xh, wg, wu, WGh, WUh);
  bucket_kernel<<<64, 1024, 0, stream>>>(tokE, tokW, cntq, bTok, bW, bFlat);
  rank_kernel<<<NE, 256, 0, stream>>>(cntq, mrows, bTok, bW, bFlat, rowTok, tokSlot);
  gemm1_kernel<<<5120 + 2048, 256, 0, stream>>>(Xh, WGh, WUh, rowTok, mrows, GU, wd, WDh);
  gemm2_kernel<<<NE * 20 * 8, 256, 0, stream>>>(GU, WDh, mrows, OE);
  combine_kernel<<<N_TOK, 128, 0, stream>>>(OE, tokSlot, tokW, out);
}